// Round 1
// baseline (23906.380 us; speedup 1.0000x reference)
//
#include <hip/hip_runtime.h>
#include <stdint.h>

// ---------------------------------------------------------------------------
// AnmNetwork: ADMM-like complex PSD iteration. B=64, m=l=64, n=128, K=10.
//  * Sita = V relu(w + minv[rank]) V^H  (second eigh mathematically redundant)
//  * Lamda_new = (1 - eta/rho) Lamda + eta * V diag(relu(w+m)-w) V^H
//  * Output depends only on state entering iteration K-1 -> 9 eigh rounds.
//  * PRNG: JAX threefry2x32 partitionable counters (bit-exact, R5).
// R13 = R12 (hermitian halving, packed params) + round-critical-path attack:
//  * LDS layout interleaved per row: re at r*258+c, im at +129 -> every cell
//    access merges to ds_read2_b32 / ds_write2_b32 (offsets 0/129), halving
//    LDS issue count. Avoids R11 b64-AoS even-bank-pair pathology (the two
//    dwords are at independent odd/even addresses; uniform 4-way worst case,
//    data-bound not issue-bound).
//  * Phase-A cell prefetch: all waves issue their 2x2-block reads BEFORE the
//    param barrier, overlapping wave-0's serial param computation (LDS pipe
//    was idle there). Addresses + conj flags cached in regs for phase B.
//  * Raw s_barrier + lgkmcnt(0)-only drain (no __syncthreads vmcnt(0)):
//    the per-round Pg global store stays in flight; visibility at kernel end
//    is sufficient (consumed only by the next dispatch).
//  * (p,q) row trackers per slot maintained incrementally (wrap inc/dec),
//    no per-round %127, no p|q sprm packing.
//  * replay: row stride 20 dwords (16B aligned) -> 4x ds_read_b128 +
//    4x ds_write_b128 per rotation instead of 32 b32. float4 U staging.
//  * A fill via float4 global loads; writeback canonical-upper only (lower
//    triangle is never read by ldc/rankd; assemble rewrites it each iter).
// State (Theta/Lamda), PRNG, u, writeout stay fp64. SWEEPS=7.
// ---------------------------------------------------------------------------

#define BATCH 64
#define MDIM 64
#define LDIM 64
#define NDIM 128
#define NSQ (NDIM * NDIM)
#define KITER 10
#define SWEEPS 7
#define RS2 258                                 // dwords/row: re c at +c, im at +129+c
#define JAC_LDS_BYTES (NDIM * RS2 * (int)sizeof(float))   // 132,096 B
#define RRS 20                                  // replay row stride (dwords, 80B = 16B-aligned)
#define OUT_ELEMS 266240   // 64*64*64 (T) + 64*64 (uvec), f32 real parts

// ----------------------------- threefry2x32 --------------------------------
__device__ __forceinline__ void tf_block(unsigned k0, unsigned k1,
                                         unsigned& x0, unsigned& x1) {
  unsigned k2 = k0 ^ k1 ^ 0x1BD11BDAu;
  x0 += k0; x1 += k1;
#define TF_R(r) { x0 += x1; x1 = (x1 << (r)) | (x1 >> (32 - (r))); x1 ^= x0; }
  TF_R(13) TF_R(15) TF_R(26) TF_R(6)
  x0 += k1; x1 += k2 + 1u;
  TF_R(17) TF_R(29) TF_R(16) TF_R(24)
  x0 += k2; x1 += k0 + 2u;
  TF_R(13) TF_R(15) TF_R(26) TF_R(6)
  x0 += k0; x1 += k1 + 3u;
  TF_R(17) TF_R(29) TF_R(16) TF_R(24)
  x0 += k1; x1 += k2 + 4u;
  TF_R(13) TF_R(15) TF_R(26) TF_R(6)
  x0 += k2; x1 += k0 + 5u;
#undef TF_R
}

// ------------------------------- erfinv (f64) ------------------------------
__device__ double erfinv_d(double x) {
  double w = -log1p(-x * x);
  double p;
  if (w < 6.25) {
    w -= 3.125;
    const double c[23] = {
      -3.6444120640178196996e-21, -1.685059138182016589e-19,
      1.2858480715256400167e-18,  1.115787767802518096e-17,
      -1.333171662854620906e-16,  2.0972767875968561637e-17,
      6.6376381343583238325e-15,  -4.0545662729752068639e-14,
      -8.1519341976054721522e-14, 2.6335093153082322977e-12,
      -1.2975133253453532498e-11, -5.4154120542946279317e-11,
      1.051212273321532285e-09,   -4.1126339803469836976e-09,
      -2.9070369957882005086e-08, 4.2347877827932403518e-07,
      -1.3654692000834678645e-06, -1.3882523362786468719e-05,
      1.8673420803405714802e-04,  -7.4070253416626697512e-04,
      -6.0336708714301490533e-03, 2.4015818242558961693e-01,
      1.6536545626831027356e+00};
    p = c[0];
#pragma unroll
    for (int i = 1; i < 23; ++i) p = p * w + c[i];
  } else if (w < 16.0) {
    double s = sqrt(w) - 3.25;
    const double c[19] = {
      2.2137376921775787049e-09,  9.0756561938885390979e-08,
      -2.7517406297064545428e-07, 1.8239629214389227755e-08,
      1.5027403968909827627e-06,  -4.013867526981545969e-06,
      2.9234449089955446044e-06,  1.2475304481671778723e-05,
      -4.7318229009055733981e-05, 6.8284851459573175448e-05,
      2.4031110387097893999e-05,  -3.5503752036284748449e-04,
      9.5328937973738049703e-04,  -1.6882755560235047313e-03,
      2.4914420961078508066e-03,  -3.7512085075692412107e-03,
      5.3709145535900636051e-03,  1.0052589676941592334e+00,
      3.0838856104922207635e+00};
    p = c[0];
#pragma unroll
    for (int i = 1; i < 19; ++i) p = p * s + c[i];
  } else {
    double s = sqrt(w) - 5.0;
    const double c[17] = {
      -2.7109920616438573243e-11, -2.5556418169965252055e-10,
      1.5076572693500548083e-09,  -3.7894654401267369937e-09,
      7.6157012080783393804e-09,  -1.4960026627149240478e-08,
      2.9147953450901080826e-08,  -6.7711997758452339498e-08,
      2.2900482228026654717e-07,  -9.9298272942317002539e-07,
      4.5260625972231537039e-06,  -1.9681778105531670567e-05,
      7.5995277030017761139e-05,  -2.1503011930044477347e-04,
      -1.3871931833623122026e-04, 1.0103004648645343977e+00,
      4.8499064014085844221e+00};
    p = c[0];
#pragma unroll
    for (int i = 1; i < 17; ++i) p = p * s + c[i];
  }
  double z = p * x;
  const double spi2 = 0.8862269254527580;  // sqrt(pi)/2
  double ax = fabs(x);
#pragma unroll
  for (int nr = 0; nr < 2; ++nr) {
    if (ax > 0.9375) {
      double az = fabs(z);
      double corr = (erfc(az) - (1.0 - ax)) * spi2 * exp(az * az);
      az += corr;
      z = copysign(az, x);
    } else {
      z -= (erf(z) - x) * spi2 * exp(z * z);
    }
  }
  return z;
}

// ------------------------------- kernels -----------------------------------
__global__ void zero_kernel(double* p, size_t n) {
  size_t i = (size_t)blockIdx.x * blockDim.x + threadIdx.x;
  size_t stride = (size_t)gridDim.x * blockDim.x;
  for (; i < n; i += stride) p[i] = 0.0;
}

__global__ void prng_kernel(double* minv) {
  int tid = blockIdx.x * blockDim.x + threadIdx.x;
  if (tid >= KITER * BATCH * NDIM) return;
  int it = tid / (BATCH * NDIM);
  int i = tid % (BATCH * NDIM);
  unsigned nk0 = 0u, nk1 = (unsigned)it;
  tf_block(0u, 42u, nk0, nk1);                       // fold_in
  unsigned c0 = 0u, c1 = (unsigned)i;                // partitionable counter
  tf_block(nk0, nk1, c0, c1);
  unsigned long long bits = ((unsigned long long)c0 << 32) | (unsigned long long)c1;
  unsigned long long fb = (bits >> 12) | 0x3FF0000000000000ull;
  double f = __builtin_bit_cast(double, fb) - 1.0;
  const double lo = __builtin_bit_cast(double, 0xBFEFFFFFFFFFFFFFull);
  double uu = f * 2.0 + lo;
  if (uu < lo) uu = lo;
  minv[tid] = 1.4142135623730951 * erfinv_d(uu);
}

__global__ void compute_u_kernel(const double2* Theta, const double2* Lamda,
                                 const float* rho, const float* tau, int it,
                                 double2* u) {
  int tid = blockIdx.x * blockDim.x + threadIdx.x;
  if (tid >= BATCH * MDIM) return;
  int b = tid / MDIM, kk = tid % MDIM;
  double r = (double)rho[it], t = (double)tau[it];
  const double2* Lb = Lamda + (size_t)b * NSQ;
  const double2* Tb = Theta + (size_t)b * NSQ;
  double ar = 0.0, ai = 0.0;
  for (int i = 0; i + kk < MDIM; ++i) {
    double2 L = Lb[i * NDIM + i + kk];
    double2 Th = Tb[i * NDIM + i + kk];
    ar += L.x + r * Th.x;
    ai += L.y + r * Th.y;
  }
  if (kk == 0) ar += -(t * 0.5) * (double)MDIM;
  double s = 1.0 / ((double)(MDIM - kk) * r);
  u[b * MDIM + kk] = make_double2(ar * s, ai * s);
}

// A32 = fp32(StackM - Lamda/r) ; U32 = I
__global__ void assemble_kernel(const double2* Theta, const double2* Lamda,
                                const double2* u, const float* Yre, const float* Yim,
                                const float* rho, const float* tau, int it,
                                float2* A32, float2* U32) {
  int tid = blockIdx.x * 256 + threadIdx.x;
  if (tid >= BATCH * NSQ) return;
  int b = tid / NSQ, rem = tid % NSQ, i = rem / NDIM, j = rem % NDIM;
  double r = (double)rho[it], t = (double)tau[it];
  size_t idx = (size_t)b * NSQ + rem;
  double2 L = Lamda[idx], Th = Theta[idx];
  double axr, axi;
  if (i < MDIM && j < MDIM) {
    int d = j - i;
    double2 uv = u[b * MDIM + (d >= 0 ? d : -d)];
    double uy = (d >= 0) ? uv.y : -uv.y;
    axr = uv.x - L.x / r;
    axi = uy - L.y / r;
  } else if (i < MDIM) {
    double yr = (double)Yre[(b * MDIM + i) * LDIM + (j - MDIM)];
    double yi = (double)Yim[(b * MDIM + i) * LDIM + (j - MDIM)];
    double inv = 1.0 / (1.0 + 2.0 * r);
    axr = (yr + 2.0 * L.x + 2.0 * r * Th.x) * inv - L.x / r;
    axi = (yi + 2.0 * L.y + 2.0 * r * Th.y) * inv - L.y / r;
  } else if (j < MDIM) {
    double yr = (double)Yre[(b * MDIM + j) * LDIM + (i - MDIM)];
    double yi = -(double)Yim[(b * MDIM + j) * LDIM + (i - MDIM)];
    double inv = 1.0 / (1.0 + 2.0 * r);
    axr = (yr + 2.0 * L.x + 2.0 * r * Th.x) * inv - L.x / r;
    axi = (yi + 2.0 * L.y + 2.0 * r * Th.y) * inv - L.y / r;
  } else {
    axr = Th.x - ((i == j) ? t / (2.0 * r) : 0.0);
    axi = Th.y;
  }
  A32[idx] = make_float2((float)axr, (float)axi);
  U32[idx] = make_float2((i == j) ? 1.0f : 0.0f, 0.0f);
}

__device__ __forceinline__ int pair_p(int j, int r) {
  return (j == 0) ? 0 : 1 + (j - 1 + r) % 127;
}
__device__ __forceinline__ int pair_q(int j, int r) {
  return 1 + (126 - j + r) % 127;
}

// Raw barrier: drain own LDS ops only -- leaves global stores in flight
// (no per-round vmcnt(0) drain; visibility at kernel end suffices).
__device__ __forceinline__ void bar_lgkm() {
  asm volatile("s_waitcnt lgkmcnt(0)" ::: "memory");
  __builtin_amdgcn_s_barrier();
}

// Replay device body: wave-owned 128x8 U column chunk in LDS, zero barriers.
// Layout per row: re cols 0..7 at +0..7, im cols 0..7 at +8..15, pad to 20
// dwords (80B, 16B-aligned) -> 4x b128 reads + 4x b128 writes per rotation.
__device__ void replay_body(float* smem, float2* __restrict__ U,
                            const float2* __restrict__ params,
                            int rb, int sweep) {
  int tid = threadIdx.x, wv = tid >> 6, ln = tid & 63;
  int b = rb >> 1, half = rb & 1;
  int col0 = (half * 8 + wv) * 8;
  float* cb = smem + wv * (NDIM * RRS);
  float2* Ug = U + (size_t)b * NSQ;
  const float2* Pg = params + (size_t)b * (127 * 64);
  for (int e = ln; e < NDIM * 4; e += 64) {
    int row = e >> 2, c2 = (e & 3) * 2;
    float4 v = *(const float4*)(Ug + row * NDIM + col0 + c2);
    float* p = cb + row * RRS + c2;
    p[0] = v.x; p[1] = v.z;
    p[8] = v.y; p[9] = v.w;
  }
  for (int r0 = 0; r0 < 127; ++r0) {
    int r = (sweep & 1) ? (126 - r0) : r0;
    int p = pair_p(ln, r), q = pair_q(ln, r);
    float2 prm = Pg[r0 * 64 + ln];
    float br = prm.x, bi = prm.y;
    float cc = sqrtf(fmaxf(0.0f, 1.0f - br * br - bi * bi));
    float4* Rp = (float4*)(cb + p * RRS);
    float4* Rq = (float4*)(cb + q * RRS);
    float4 pr0 = Rp[0], pr1 = Rp[1], pim0 = Rp[2], pim1 = Rp[3];
    float4 qr0 = Rq[0], qr1 = Rq[1], qim0 = Rq[2], qim1 = Rq[3];
#define ROTC(UPX, UPY, UQX, UQY) { float upx = UPX, upy = UPY, uqx = UQX, uqy = UQY; \
    UPX = cc * upx + (br * uqx + bi * uqy);  /* U_p <- c U_p + conj(sb) U_q */       \
    UPY = cc * upy + (br * uqy - bi * uqx);                                          \
    UQX = cc * uqx - (br * upx - bi * upy);  /* U_q <- c U_q - sb U_p */             \
    UQY = cc * uqy - (br * upy + bi * upx); }
    ROTC(pr0.x, pim0.x, qr0.x, qim0.x)
    ROTC(pr0.y, pim0.y, qr0.y, qim0.y)
    ROTC(pr0.z, pim0.z, qr0.z, qim0.z)
    ROTC(pr0.w, pim0.w, qr0.w, qim0.w)
    ROTC(pr1.x, pim1.x, qr1.x, qim1.x)
    ROTC(pr1.y, pim1.y, qr1.y, qim1.y)
    ROTC(pr1.z, pim1.z, qr1.z, qim1.z)
    ROTC(pr1.w, pim1.w, qr1.w, qim1.w)
#undef ROTC
    Rp[0] = pr0; Rp[1] = pr1; Rp[2] = pim0; Rp[3] = pim1;
    Rq[0] = qr0; Rq[1] = qr1; Rq[2] = qim0; Rq[3] = qim1;
    __builtin_amdgcn_wave_barrier();
  }
  for (int e = ln; e < NDIM * 4; e += 64) {
    int row = e >> 2, c2 = (e & 3) * 2;
    float* p = cb + row * RRS + c2;
    *(float4*)(Ug + row * NDIM + col0 + c2) =
        make_float4(p[0], p[8], p[1], p[9]);
  }
}

// Combined dispatch: blocks 0..63 jacobi sweep `sweep` (params -> prmW);
// blocks 64..191 replay sweep-1 from prmR onto U (idle CUs).
// Jacobi: canonical-upper Hermitian, 2080 blocks over 512 threads
// (~4/thread, extra 32 on wave 7); interleaved re/im rows (read2/write2);
// phase-A cell prefetch overlaps wave-0 param compute; raw lgkm barriers.
__global__ __launch_bounds__(512) void combined_kernel(
    float2* __restrict__ A, float2* __restrict__ U,
    float2* __restrict__ prmW, const float2* __restrict__ prmR,
    const double* __restrict__ minv, int it, int sweep, int last,
    double* __restrict__ d1, double* __restrict__ d2) {
  extern __shared__ float smem[];
  if (blockIdx.x >= BATCH) {
    if (sweep > 0) replay_body(smem, U, prmR, blockIdx.x - BATCH, sweep - 1);
    return;
  }
  float* sA = smem;               // [128 rows][re 0..127 | pad | im at +129]
  __shared__ float4 sprm[64];     // {c, br, bi, 0}
  int b = blockIdx.x, tid = threadIdx.x;
  float2* Ag = A + (size_t)b * NSQ;
  float2* Pg = prmW + (size_t)b * (127 * 64);
  const float4* Ag4 = (const float4*)Ag;
  for (int i2 = tid; i2 < NSQ / 2; i2 += 512) {
    float4 v = Ag4[i2];
    int r = i2 >> 6, c = (i2 & 63) * 2;
    float* p = sA + r * RS2 + c;
    p[0] = v.x; p[1] = v.z;          // re pair -> write2
    p[129] = v.y; p[130] = v.w;      // im pair -> write2
  }
  // decode this thread's canonical slot-pair blocks (i<=j), fixed all rounds
  bool has5 = (tid >= 480);
  int bi_[5], bj_[5];
#pragma unroll
  for (int k = 0; k < 4; ++k) {
    int e = tid + 512 * k;
    int i = 0;
    while (i < 63 && (64 * (i + 1) - ((i + 1) * i) / 2) <= e) ++i;
    bi_[k] = i;
    bj_[k] = i + (e - (64 * i - (i * (i - 1)) / 2));
  }
  bi_[4] = 0; bj_[4] = 0;
  if (has5) {
    int e = 2048 + (tid - 480);
    int i = 0;
    while (i < 63 && (64 * (i + 1) - ((i + 1) * i) / 2) <= e) ++i;
    bi_[4] = i;
    bj_[4] = i + (e - (64 * i - (i * (i - 1)) / 2));
  }
  // incremental slot->row trackers (no per-round %127)
  const bool fwd = !(sweep & 1);
  int r_init = fwd ? 0 : 126;
  int pi_[5], qi_[5], pj_[5], qj_[5];
#pragma unroll
  for (int k = 0; k < 5; ++k) {
    pi_[k] = pair_p(bi_[k], r_init); qi_[k] = pair_q(bi_[k], r_init);
    pj_[k] = pair_p(bj_[k], r_init); qj_[k] = pair_q(bj_[k], r_init);
  }
  int lane = tid & 63;
  int pp = pair_p(lane, r_init), qq = pair_q(lane, r_init);
  bar_lgkm();
  for (int r0 = 0; r0 < 127; ++r0) {
    // ---- phase A: prefetch 2x2 cells (all waves) + wave-0 params ----
    float2 C00[5], C01[5], C10[5], C11[5];
    int a00[5], a01[5], a10[5], a11[5];
    bool s00[5], s01[5], s10[5], s11[5];
    auto cellA = [&](int rr, int cc2, int& a, bool& sw) {
      int lo = rr <= cc2 ? rr : cc2, hi = rr <= cc2 ? cc2 : rr;
      a = lo * RS2 + hi;
      sw = rr > cc2;
    };
    auto ldA = [&](int a, bool sw) {
      float x = sA[a], y = sA[a + 129];     // -> ds_read2_b32 0/129
      return make_float2(x, sw ? -y : y);
    };
    auto PRE = [&](int k) {
      cellA(pi_[k], pj_[k], a00[k], s00[k]); C00[k] = ldA(a00[k], s00[k]);
      cellA(pi_[k], qj_[k], a01[k], s01[k]); C01[k] = ldA(a01[k], s01[k]);
      cellA(qi_[k], pj_[k], a10[k], s10[k]); C10[k] = ldA(a10[k], s10[k]);
      cellA(qi_[k], qj_[k], a11[k], s11[k]); C11[k] = ldA(a11[k], s11[k]);
    };
    PRE(0); PRE(1); PRE(2); PRE(3);
    if (has5) PRE(4);
    if (tid < 64) {
      float app = sA[pp * RS2 + pp], aqq = sA[qq * RS2 + qq];
      int ga; bool gs;
      cellA(pp, qq, ga, gs);
      float gx = sA[ga], gy = sA[ga + 129];
      if (gs) gy = -gy;
      float ag2 = gx * gx + gy * gy;
      float cc = 1.0f, br = 0.0f, bii = 0.0f;
      if (ag2 > 1e-24f) {
        float ag = sqrtf(ag2);
        float ta = (aqq - app) / (2.0f * ag);
        float tt = -copysignf(1.0f, ta) / (fabsf(ta) + sqrtf(1.0f + ta * ta));
        cc = 1.0f / sqrtf(1.0f + tt * tt);
        float tcag = tt * cc / ag;
        br = gx * tcag; bii = gy * tcag;
      }
      sprm[tid] = make_float4(cc, br, bii, 0.0f);
      Pg[r0 * 64 + tid] = make_float2(br, bii);   // fire-and-forget
    }
    bar_lgkm();   // params visible; all pre-round A reads drained (WAR)
    // ---- phase B: rotate + write (cached addresses) ----
    auto stA = [&](int a, bool sw, float zr, float zi) {
      sA[a] = zr;                            // -> ds_write2_b32 0/129
      sA[a + 129] = sw ? -zi : zi;
    };
    auto UPD = [&](int k) {
      float4 Pi = sprm[bi_[k]], Pj = sprm[bj_[k]];
      float ci = Pi.x, bri = Pi.y, bii = Pi.z;
      float cj = Pj.x, brj = Pj.y, bij = Pj.z;
      float2 B00 = C00[k], B01 = C01[k], B10 = C10[k], B11 = C11[k];
      // left: T = L_i * B
      float t00r = ci * B00.x + (bri * B10.x - bii * B10.y);
      float t00i = ci * B00.y + (bri * B10.y + bii * B10.x);
      float t01r = ci * B01.x + (bri * B11.x - bii * B11.y);
      float t01i = ci * B01.y + (bri * B11.y + bii * B11.x);
      float t10r = ci * B10.x - (bri * B00.x + bii * B00.y);
      float t10i = ci * B10.y - (bri * B00.y - bii * B00.x);
      float t11r = ci * B11.x - (bri * B01.x + bii * B01.y);
      float t11i = ci * B11.y - (bri * B01.y - bii * B01.x);
      // right: C = T * R_j
      stA(a00[k], s00[k],
          cj * t00r + (brj * t01r + bij * t01i),
          cj * t00i + (brj * t01i - bij * t01r));
      stA(a01[k], s01[k],
          cj * t01r - (brj * t00r - bij * t00i),
          cj * t01i - (brj * t00i + bij * t00r));
      stA(a10[k], s10[k],
          cj * t10r + (brj * t11r + bij * t11i),
          cj * t10i + (brj * t11i - bij * t11r));
      stA(a11[k], s11[k],
          cj * t11r - (brj * t10r - bij * t10i),
          cj * t11i - (brj * t10i + bij * t10r));
    };
    UPD(0); UPD(1); UPD(2); UPD(3);
    if (has5) UPD(4);
    bar_lgkm();   // RAW: writes visible before next round's reads
    // ---- step trackers to next round ----
#pragma unroll
    for (int k = 0; k < 5; ++k) {
      if (fwd) {
        pi_[k] = (pi_[k] == 0) ? 0 : ((pi_[k] == 127) ? 1 : pi_[k] + 1);
        qi_[k] = (qi_[k] == 127) ? 1 : qi_[k] + 1;
        pj_[k] = (pj_[k] == 0) ? 0 : ((pj_[k] == 127) ? 1 : pj_[k] + 1);
        qj_[k] = (qj_[k] == 127) ? 1 : qj_[k] + 1;
      } else {
        pi_[k] = (pi_[k] == 0) ? 0 : ((pi_[k] == 1) ? 127 : pi_[k] - 1);
        qi_[k] = (qi_[k] == 1) ? 127 : qi_[k] - 1;
        pj_[k] = (pj_[k] == 0) ? 0 : ((pj_[k] == 1) ? 127 : pj_[k] - 1);
        qj_[k] = (qj_[k] == 1) ? 127 : qj_[k] - 1;
      }
    }
    if (fwd) {
      pp = (pp == 0) ? 0 : ((pp == 127) ? 1 : pp + 1);
      qq = (qq == 127) ? 1 : qq + 1;
    } else {
      pp = (pp == 0) ? 0 : ((pp == 1) ? 127 : pp - 1);
      qq = (qq == 1) ? 127 : qq - 1;
    }
  }
  // writeback: canonical upper only (lower never consumed; assemble rewrites)
  for (int i = tid; i < NSQ; i += 512) {
    int r = i >> 7, c = i & 127;
    if (c >= r)
      Ag[i] = make_float2(sA[r * RS2 + c], sA[r * RS2 + 129 + c]);
  }
  if (last && tid < NDIM) {   // fused rankd (diag is canonical)
    float wj = sA[tid * RS2 + tid];
    int rank = 0;
    for (int k2 = 0; k2 < NDIM; ++k2) {
      float wk = sA[k2 * RS2 + k2];
      rank += (wk < wj) || (wk == wj && k2 < tid);
    }
    double mv = minv[(it * BATCH + b) * NDIM + rank];
    double v = (double)wj + mv;
    if (v < 0.0) v = 0.0;
    d1[b * NDIM + tid] = v;
    d2[b * NDIM + tid] = v - (double)wj;
  }
}

// Final replay of the last sweep (before update_kernel).
__global__ __launch_bounds__(512) void replay_kernel(
    float2* __restrict__ U, const float2* __restrict__ params, int sweep) {
  extern __shared__ float smem[];
  replay_body(smem, U, params, blockIdx.x, sweep);
}

// Theta = V diag(d1) V^H ; Lamda = (1-e/r) Lamda + e * V diag(d2) V^H.
__global__ __launch_bounds__(256) void update_kernel(
    const float2* U, const double* d1, const double* d2,
    const float* rho, const float* eta, int it,
    double2* Theta, double2* Lamda) {
  __shared__ float ViRe[32][33], ViIm[32][33];
  __shared__ float VkRe[32][33], VkIm[32][33];
  __shared__ double s1[32], s2[32];
  int blk = blockIdx.x;
  int b = blk >> 4, tile = blk & 15, ti = tile >> 2, tk = tile & 3;
  int tid = threadIdx.x;
  int lk = tid & 31, lig = tid >> 5;
  double r = (double)rho[it], e = (double)eta[it];
  double a1x[4] = {0, 0, 0, 0}, a1y[4] = {0, 0, 0, 0};
  double a2x[4] = {0, 0, 0, 0}, a2y[4] = {0, 0, 0, 0};
  const float2* Ub = U + (size_t)b * NSQ;
  for (int jc = 0; jc < 4; ++jc) {
    for (int e2 = tid; e2 < 1024; e2 += 256) {
      int rr = e2 & 31, cc2 = e2 >> 5;
      float2 v1 = Ub[(jc * 32 + cc2) * NDIM + ti * 32 + rr];
      ViRe[rr][cc2] = v1.x; ViIm[rr][cc2] = v1.y;
      float2 v2 = Ub[(jc * 32 + cc2) * NDIM + tk * 32 + rr];
      VkRe[rr][cc2] = v2.x; VkIm[rr][cc2] = v2.y;
    }
    if (tid < 32) {
      s1[tid] = d1[b * NDIM + jc * 32 + tid];
      s2[tid] = d2[b * NDIM + jc * 32 + tid];
    }
    __syncthreads();
#pragma unroll
    for (int uo = 0; uo < 4; ++uo) {
      int li = lig + uo * 8;
      double ax = a1x[uo], ay = a1y[uo], bx = a2x[uo], by = a2y[uo];
      for (int jj = 0; jj < 32; ++jj) {
        float var = ViRe[li][jj], vai = ViIm[li][jj];
        float vbr = VkRe[lk][jj], vbi = VkIm[lk][jj];
        double pr = (double)(var * vbr + vai * vbi);
        double pi = (double)(vai * vbr - var * vbi);
        ax += s1[jj] * pr; ay += s1[jj] * pi;
        bx += s2[jj] * pr; by += s2[jj] * pi;
      }
      a1x[uo] = ax; a1y[uo] = ay; a2x[uo] = bx; a2y[uo] = by;
    }
    __syncthreads();
  }
  double lf = 1.0 - e / r;
#pragma unroll
  for (int uo = 0; uo < 4; ++uo) {
    int gi = ti * 32 + lig + uo * 8, gk = tk * 32 + lk;
    size_t idx = (size_t)b * NSQ + gi * NDIM + gk;
    Theta[idx] = make_double2(a1x[uo], a1y[uo]);
    double2 Lold = Lamda[idx];
    Lamda[idx] = make_double2(lf * Lold.x + e * a2x[uo], lf * Lold.y + e * a2y[uo]);
  }
}

// OUTPUT (float32 real parts): T[i][j] = u[|i-j|].re ; uvec.re = u.re
__global__ void writeout_kernel(const double2* u, float* out) {
  int tid = blockIdx.x * 256 + threadIdx.x;
  if (tid >= OUT_ELEMS) return;
  double re;
  if (tid < BATCH * MDIM * MDIM) {
    int b = tid >> 12, rem = tid & 4095, i = rem >> 6, j = rem & 63;
    int d = j - i;
    re = u[b * MDIM + (d >= 0 ? d : -d)].x;
  } else {
    int k2 = tid - BATCH * MDIM * MDIM;
    int b = k2 >> 6, kk = k2 & 63;
    re = u[b * MDIM + kk].x;
  }
  out[tid] = (float)re;
}

// ------------------------------- launch ------------------------------------
extern "C" void kernel_launch(void* const* d_in, const int* in_sizes, int n_in,
                              void* d_out, int out_size, void* d_ws, size_t ws_size,
                              hipStream_t stream) {
  const float* Yre = (const float*)d_in[0];
  const float* Yim = (const float*)d_in[1];
  const float* rho = (const float*)d_in[2];
  const float* tau = (const float*)d_in[3];
  const float* eta = (const float*)d_in[4];
  float* out = (float*)d_out;

  char* ws = (char*)d_ws;
  size_t off = 0;
  auto take = [&](size_t bytes) -> char* {
    char* p = ws + off;
    off += (bytes + 255) & ~(size_t)255;
    return p;
  };
  double2* u     = (double2*)take((size_t)BATCH * MDIM * sizeof(double2));
  double*  minv  = (double*)take((size_t)KITER * BATCH * NDIM * sizeof(double));
  double*  d1    = (double*)take((size_t)BATCH * NDIM * sizeof(double));
  double*  d2    = (double*)take((size_t)BATCH * NDIM * sizeof(double));
  double2* Lamda = (double2*)take((size_t)BATCH * NSQ * sizeof(double2));  // 16.8 MB
  double2* Theta = (double2*)take((size_t)BATCH * NSQ * sizeof(double2));  // 16.8 MB
  float2*  A32   = (float2*)take((size_t)BATCH * NSQ * sizeof(float2));    //  8.4 MB
  float2*  U32   = (float2*)take((size_t)BATCH * NSQ * sizeof(float2));    //  8.4 MB
  float2*  prm0  = (float2*)take((size_t)BATCH * 127 * 64 * sizeof(float2)); // 4.2 MB
  float2*  prm1  = (float2*)take((size_t)BATCH * 127 * 64 * sizeof(float2)); // 4.2 MB
  float2*  prmB[2] = {prm0, prm1};
  (void)in_sizes; (void)n_in; (void)ws_size; (void)out_size;  // ~59.7 MB total

  hipFuncSetAttribute((const void*)combined_kernel,
                      hipFuncAttributeMaxDynamicSharedMemorySize, JAC_LDS_BYTES);
  hipFuncSetAttribute((const void*)replay_kernel,
                      hipFuncAttributeMaxDynamicSharedMemorySize, JAC_LDS_BYTES);

  zero_kernel<<<2048, 256, 0, stream>>>((double*)Theta, (size_t)BATCH * NSQ * 2);
  zero_kernel<<<2048, 256, 0, stream>>>((double*)Lamda, (size_t)BATCH * NSQ * 2);
  prng_kernel<<<(KITER * BATCH * NDIM + 255) / 256, 256, 0, stream>>>(minv);

  for (int it = 0; it < KITER - 1; ++it) {
    compute_u_kernel<<<16, 256, 0, stream>>>(Theta, Lamda, rho, tau, it, u);
    assemble_kernel<<<BATCH * NSQ / 256, 256, 0, stream>>>(Theta, Lamda, u, Yre, Yim,
                                                           rho, tau, it, A32, U32);
    for (int s = 0; s < SWEEPS; ++s) {
      combined_kernel<<<BATCH + 2 * BATCH, 512, JAC_LDS_BYTES, stream>>>(
          A32, U32, prmB[s & 1], prmB[(s + 1) & 1], minv, it, s,
          (s == SWEEPS - 1) ? 1 : 0, d1, d2);
    }
    replay_kernel<<<2 * BATCH, 512, JAC_LDS_BYTES, stream>>>(
        U32, prmB[(SWEEPS - 1) & 1], SWEEPS - 1);
    update_kernel<<<BATCH * 16, 256, 0, stream>>>(U32, d1, d2, rho, eta, it, Theta, Lamda);
  }
  compute_u_kernel<<<16, 256, 0, stream>>>(Theta, Lamda, rho, tau, KITER - 1, u);
  writeout_kernel<<<(OUT_ELEMS + 255) / 256, 256, 0, stream>>>(u, out);
}

// Round 2
// 21710.672 us; speedup vs baseline: 1.1011x; 1.1011x over previous
//
#include <hip/hip_runtime.h>
#include <stdint.h>

// ---------------------------------------------------------------------------
// AnmNetwork: ADMM-like complex PSD iteration. B=64, m=l=64, n=128, K=10.
//  * Sita = V relu(w + minv[rank]) V^H  (second eigh mathematically redundant)
//  * Lamda_new = (1 - eta/rho) Lamda + eta * V diag(relu(w+m)-w) V^H
//  * Output depends only on state entering iteration K-1 -> 9 eigh rounds.
//  * PRNG: JAX threefry2x32 partitionable counters (bit-exact, R5).
// R14 = R12 round body (R13's phase-split prefetch regressed: serialized
// load/compute bursts + VGPR 36->60; reverted verbatim) + SWEEP FUSION:
//  * ONE dispatch per iteration (grid 192): jacobi blocks 0..63 keep A
//    LDS-resident across all 7 sweeps; replay blocks 64..191 keep their
//    128x8 U chunk LDS-resident across all 7 sweeps (init U=I in LDS,
//    assemble no longer touches U32).
//  * A is NEVER written back (only d1/d2 leave; assemble rebuilds A next
//    iteration). Saves 7x A reload + 7x upper writeback per iteration.
//  * params: 7 per-sweep buffers (29.4 MB); jacobi releases flag[b][s]
//    (device-scope __hip_atomic release, value it+1, monotone -> zeroed
//    once) after each sweep's __syncthreads (which drains vmcnt); replay
//    waves acquire-spin then read. Producer never waits -> deadlock-free
//    under any block scheduling; 7 buffers -> no overwrite hazard.
//  * Rotation order and params bit-identical to R12 -> output identical.
// State (Theta/Lamda), PRNG, u, writeout stay fp64. SWEEPS=7.
// ---------------------------------------------------------------------------

#define BATCH 64
#define MDIM 64
#define LDIM 64
#define NDIM 128
#define NSQ (NDIM * NDIM)
#define KITER 10
#define SWEEPS 7
#define RS 129                                  // LDS row stride (floats, SoA)
#define JAC_LDS_BYTES (2 * NDIM * RS * (int)sizeof(float))   // 132,096 B
#define RCH 9                                   // replay chunk col stride
#define OUT_ELEMS 266240   // 64*64*64 (T) + 64*64 (uvec), f32 real parts

// ----------------------------- threefry2x32 --------------------------------
__device__ __forceinline__ void tf_block(unsigned k0, unsigned k1,
                                         unsigned& x0, unsigned& x1) {
  unsigned k2 = k0 ^ k1 ^ 0x1BD11BDAu;
  x0 += k0; x1 += k1;
#define TF_R(r) { x0 += x1; x1 = (x1 << (r)) | (x1 >> (32 - (r))); x1 ^= x0; }
  TF_R(13) TF_R(15) TF_R(26) TF_R(6)
  x0 += k1; x1 += k2 + 1u;
  TF_R(17) TF_R(29) TF_R(16) TF_R(24)
  x0 += k2; x1 += k0 + 2u;
  TF_R(13) TF_R(15) TF_R(26) TF_R(6)
  x0 += k0; x1 += k1 + 3u;
  TF_R(17) TF_R(29) TF_R(16) TF_R(24)
  x0 += k1; x1 += k2 + 4u;
  TF_R(13) TF_R(15) TF_R(26) TF_R(6)
  x0 += k2; x1 += k0 + 5u;
#undef TF_R
}

// ------------------------------- erfinv (f64) ------------------------------
__device__ double erfinv_d(double x) {
  double w = -log1p(-x * x);
  double p;
  if (w < 6.25) {
    w -= 3.125;
    const double c[23] = {
      -3.6444120640178196996e-21, -1.685059138182016589e-19,
      1.2858480715256400167e-18,  1.115787767802518096e-17,
      -1.333171662854620906e-16,  2.0972767875968561637e-17,
      6.6376381343583238325e-15,  -4.0545662729752068639e-14,
      -8.1519341976054721522e-14, 2.6335093153082322977e-12,
      -1.2975133253453532498e-11, -5.4154120542946279317e-11,
      1.051212273321532285e-09,   -4.1126339803469836976e-09,
      -2.9070369957882005086e-08, 4.2347877827932403518e-07,
      -1.3654692000834678645e-06, -1.3882523362786468719e-05,
      1.8673420803405714802e-04,  -7.4070253416626697512e-04,
      -6.0336708714301490533e-03, 2.4015818242558961693e-01,
      1.6536545626831027356e+00};
    p = c[0];
#pragma unroll
    for (int i = 1; i < 23; ++i) p = p * w + c[i];
  } else if (w < 16.0) {
    double s = sqrt(w) - 3.25;
    const double c[19] = {
      2.2137376921775787049e-09,  9.0756561938885390979e-08,
      -2.7517406297064545428e-07, 1.8239629214389227755e-08,
      1.5027403968909827627e-06,  -4.013867526981545969e-06,
      2.9234449089955446044e-06,  1.2475304481671778723e-05,
      -4.7318229009055733981e-05, 6.8284851459573175448e-05,
      2.4031110387097893999e-05,  -3.5503752036284748449e-04,
      9.5328937973738049703e-04,  -1.6882755560235047313e-03,
      2.4914420961078508066e-03,  -3.7512085075692412107e-03,
      5.3709145535900636051e-03,  1.0052589676941592334e+00,
      3.0838856104922207635e+00};
    p = c[0];
#pragma unroll
    for (int i = 1; i < 19; ++i) p = p * s + c[i];
  } else {
    double s = sqrt(w) - 5.0;
    const double c[17] = {
      -2.7109920616438573243e-11, -2.5556418169965252055e-10,
      1.5076572693500548083e-09,  -3.7894654401267369937e-09,
      7.6157012080783393804e-09,  -1.4960026627149240478e-08,
      2.9147953450901080826e-08,  -6.7711997758452339498e-08,
      2.2900482228026654717e-07,  -9.9298272942317002539e-07,
      4.5260625972231537039e-06,  -1.9681778105531670567e-05,
      7.5995277030017761139e-05,  -2.1503011930044477347e-04,
      -1.3871931833623122026e-04, 1.0103004648645343977e+00,
      4.8499064014085844221e+00};
    p = c[0];
#pragma unroll
    for (int i = 1; i < 17; ++i) p = p * s + c[i];
  }
  double z = p * x;
  const double spi2 = 0.8862269254527580;  // sqrt(pi)/2
  double ax = fabs(x);
#pragma unroll
  for (int nr = 0; nr < 2; ++nr) {
    if (ax > 0.9375) {
      double az = fabs(z);
      double corr = (erfc(az) - (1.0 - ax)) * spi2 * exp(az * az);
      az += corr;
      z = copysign(az, x);
    } else {
      z -= (erf(z) - x) * spi2 * exp(z * z);
    }
  }
  return z;
}

// ------------------------------- kernels -----------------------------------
__global__ void zero_kernel(double* p, size_t n) {
  size_t i = (size_t)blockIdx.x * blockDim.x + threadIdx.x;
  size_t stride = (size_t)gridDim.x * blockDim.x;
  for (; i < n; i += stride) p[i] = 0.0;
}

__global__ void flags_zero_kernel(unsigned* flags) {
  int tid = threadIdx.x;
  if (tid < BATCH * SWEEPS) flags[tid] = 0u;
}

__global__ void prng_kernel(double* minv) {
  int tid = blockIdx.x * blockDim.x + threadIdx.x;
  if (tid >= KITER * BATCH * NDIM) return;
  int it = tid / (BATCH * NDIM);
  int i = tid % (BATCH * NDIM);
  unsigned nk0 = 0u, nk1 = (unsigned)it;
  tf_block(0u, 42u, nk0, nk1);                       // fold_in
  unsigned c0 = 0u, c1 = (unsigned)i;                // partitionable counter
  tf_block(nk0, nk1, c0, c1);
  unsigned long long bits = ((unsigned long long)c0 << 32) | (unsigned long long)c1;
  unsigned long long fb = (bits >> 12) | 0x3FF0000000000000ull;
  double f = __builtin_bit_cast(double, fb) - 1.0;
  const double lo = __builtin_bit_cast(double, 0xBFEFFFFFFFFFFFFFull);
  double uu = f * 2.0 + lo;
  if (uu < lo) uu = lo;
  minv[tid] = 1.4142135623730951 * erfinv_d(uu);
}

__global__ void compute_u_kernel(const double2* Theta, const double2* Lamda,
                                 const float* rho, const float* tau, int it,
                                 double2* u) {
  int tid = blockIdx.x * blockDim.x + threadIdx.x;
  if (tid >= BATCH * MDIM) return;
  int b = tid / MDIM, kk = tid % MDIM;
  double r = (double)rho[it], t = (double)tau[it];
  const double2* Lb = Lamda + (size_t)b * NSQ;
  const double2* Tb = Theta + (size_t)b * NSQ;
  double ar = 0.0, ai = 0.0;
  for (int i = 0; i + kk < MDIM; ++i) {
    double2 L = Lb[i * NDIM + i + kk];
    double2 Th = Tb[i * NDIM + i + kk];
    ar += L.x + r * Th.x;
    ai += L.y + r * Th.y;
  }
  if (kk == 0) ar += -(t * 0.5) * (double)MDIM;
  double s = 1.0 / ((double)(MDIM - kk) * r);
  u[b * MDIM + kk] = make_double2(ar * s, ai * s);
}

// A32 = fp32(StackM - Lamda/r)   (U init moved into combined_all: U = I)
__global__ void assemble_kernel(const double2* Theta, const double2* Lamda,
                                const double2* u, const float* Yre, const float* Yim,
                                const float* rho, const float* tau, int it,
                                float2* A32) {
  int tid = blockIdx.x * 256 + threadIdx.x;
  if (tid >= BATCH * NSQ) return;
  int b = tid / NSQ, rem = tid % NSQ, i = rem / NDIM, j = rem % NDIM;
  double r = (double)rho[it], t = (double)tau[it];
  size_t idx = (size_t)b * NSQ + rem;
  double2 L = Lamda[idx], Th = Theta[idx];
  double axr, axi;
  if (i < MDIM && j < MDIM) {
    int d = j - i;
    double2 uv = u[b * MDIM + (d >= 0 ? d : -d)];
    double uy = (d >= 0) ? uv.y : -uv.y;
    axr = uv.x - L.x / r;
    axi = uy - L.y / r;
  } else if (i < MDIM) {
    double yr = (double)Yre[(b * MDIM + i) * LDIM + (j - MDIM)];
    double yi = (double)Yim[(b * MDIM + i) * LDIM + (j - MDIM)];
    double inv = 1.0 / (1.0 + 2.0 * r);
    axr = (yr + 2.0 * L.x + 2.0 * r * Th.x) * inv - L.x / r;
    axi = (yi + 2.0 * L.y + 2.0 * r * Th.y) * inv - L.y / r;
  } else if (j < MDIM) {
    double yr = (double)Yre[(b * MDIM + j) * LDIM + (i - MDIM)];
    double yi = -(double)Yim[(b * MDIM + j) * LDIM + (i - MDIM)];
    double inv = 1.0 / (1.0 + 2.0 * r);
    axr = (yr + 2.0 * L.x + 2.0 * r * Th.x) * inv - L.x / r;
    axi = (yi + 2.0 * L.y + 2.0 * r * Th.y) * inv - L.y / r;
  } else {
    axr = Th.x - ((i == j) ? t / (2.0 * r) : 0.0);
    axi = Th.y;
  }
  A32[idx] = make_float2((float)axr, (float)axi);
}

__device__ __forceinline__ int pair_p(int j, int r) {
  return (j == 0) ? 0 : 1 + (j - 1 + r) % 127;
}
__device__ __forceinline__ int pair_q(int j, int r) {
  return 1 + (126 - j + r) % 127;
}

// Canonical-upper accessors (SoA planes sAre/sAim, stride RS).
__device__ __forceinline__ float2 ldc(const float* sAre, const float* sAim,
                                      int r, int c) {
  int rr = r <= c ? r : c, cc = r <= c ? c : r;
  float2 v = make_float2(sAre[rr * RS + cc], sAim[rr * RS + cc]);
  if (r > c) v.y = -v.y;
  return v;
}
__device__ __forceinline__ void stc(float* sAre, float* sAim,
                                    int r, int c, float zr, float zi) {
  int rr = r <= c ? r : c, cc = r <= c ? c : r;
  sAre[rr * RS + cc] = zr;
  sAim[rr * RS + cc] = (r <= c) ? zi : -zi;
}

// Fused dispatch: blocks 0..63 jacobi (all 7 sweeps, A LDS-resident, params
// released per sweep via device-scope flags); blocks 64..191 replay (U chunk
// LDS-resident across all 7 sweeps, init to I, acquire-spin per sweep).
// Jacobi round body is R12's proven structure (canonical-upper Hermitian,
// 2080 slot-pair blocks over 512 threads, packed float4 params in LDS).
__global__ __launch_bounds__(512) void combined_all_kernel(
    const float2* __restrict__ A, float2* __restrict__ U,
    float2* __restrict__ prm,        // [SWEEPS][BATCH][127][64]
    unsigned* __restrict__ flags,    // [BATCH][SWEEPS]
    const double* __restrict__ minv, int it,
    double* __restrict__ d1, double* __restrict__ d2) {
  extern __shared__ float smem[];
  int tid = threadIdx.x;

  if (blockIdx.x >= BATCH) {
    // ------------------------- replay path --------------------------------
    int rb = blockIdx.x - BATCH;
    int wv = tid >> 6, ln = tid & 63;
    int b = rb >> 1, half = rb & 1;
    int col0 = (half * 8 + wv) * 8;
    float* cre = smem + wv * (2 * NDIM * RCH);
    float* cim = cre + NDIM * RCH;
    // U = I (chunk init in LDS; no global load, assemble no longer writes U)
    for (int e = ln; e < NDIM * 8; e += 64) {
      int row = e >> 3, c = e & 7;
      cre[row * RCH + c] = (row == col0 + c) ? 1.0f : 0.0f;
      cim[row * RCH + c] = 0.0f;
    }
    for (int s = 0; s < SWEEPS; ++s) {
      const float2* Pg = prm + ((size_t)s * BATCH + b) * (127 * 64);
      if (ln == 0) {   // per-wave acquire spin (waves are independent)
        while (__hip_atomic_load(&flags[b * SWEEPS + s], __ATOMIC_ACQUIRE,
                                 __HIP_MEMORY_SCOPE_AGENT) != (unsigned)(it + 1)) {
          __builtin_amdgcn_s_sleep(8);
        }
      }
      // wave64 lockstep reconvergence: all lanes proceed after ln0's acquire
      for (int r0 = 0; r0 < 127; ++r0) {
        int r = (s & 1) ? (126 - r0) : r0;
        int p = pair_p(ln, r), q = pair_q(ln, r);
        float2 prmv = Pg[r0 * 64 + ln];
        float br = prmv.x, bi = prmv.y;
        float cc = sqrtf(fmaxf(0.0f, 1.0f - br * br - bi * bi));
#pragma unroll
        for (int c = 0; c < 8; ++c) {
          int ip = p * RCH + c, iq = q * RCH + c;
          float upx = cre[ip], upy = cim[ip];
          float uqx = cre[iq], uqy = cim[iq];
          cre[ip] = cc * upx + (br * uqx + bi * uqy);   // U_p <- c U_p + conj(sb) U_q
          cim[ip] = cc * upy + (br * uqy - bi * uqx);
          cre[iq] = cc * uqx - (br * upx - bi * upy);   // U_q <- c U_q - sb U_p
          cim[iq] = cc * uqy - (br * upy + bi * upx);
        }
        __builtin_amdgcn_wave_barrier();
      }
    }
    float2* Ug = U + (size_t)b * NSQ;
    for (int e = ln; e < NDIM * 8; e += 64) {
      int row = e >> 3, c = e & 7;
      Ug[row * NDIM + col0 + c] = make_float2(cre[row * RCH + c], cim[row * RCH + c]);
    }
    return;
  }

  // --------------------------- jacobi path --------------------------------
  float* sAre = smem;             // 128 x 129
  float* sAim = smem + NDIM * RS;
  __shared__ float4 sprm[64];     // {c, br, bi, bitcast(p | q<<8)}
  int b = blockIdx.x;
  const float2* Ag = A + (size_t)b * NSQ;
  for (int i = tid; i < NSQ; i += 512) {
    float2 a = Ag[i];
    sAre[(i >> 7) * RS + (i & 127)] = a.x;
    sAim[(i >> 7) * RS + (i & 127)] = a.y;
  }
  // decode this thread's canonical slot-pair blocks (i<=j), fixed all rounds
  int nb = (tid >= 480) ? 5 : 4;
  int bi_[5], bj_[5];
#pragma unroll
  for (int k = 0; k < 4; ++k) {
    int e = tid + 512 * k;
    int i = 0;
    while (i < 63 && (64 * (i + 1) - ((i + 1) * i) / 2) <= e) ++i;
    bi_[k] = i;
    bj_[k] = i + (e - (64 * i - (i * (i - 1)) / 2));
  }
  if (nb == 5) {
    int e = 2048 + (tid - 480);
    int i = 0;
    while (i < 63 && (64 * (i + 1) - ((i + 1) * i) / 2) <= e) ++i;
    bi_[4] = i;
    bj_[4] = i + (e - (64 * i - (i * (i - 1)) / 2));
  }
  __syncthreads();

  for (int s = 0; s < SWEEPS; ++s) {
    float2* Pg = prm + ((size_t)s * BATCH + b) * (127 * 64);
    for (int r0 = 0; r0 < 127; ++r0) {
      int r = (s & 1) ? (126 - r0) : r0;
      if (tid < 64) {
        int p = pair_p(tid, r), q = pair_q(tid, r);
        float app = sAre[p * RS + p], aqq = sAre[q * RS + q];
        float2 g = ldc(sAre, sAim, p, q);
        float ag2 = g.x * g.x + g.y * g.y;
        float cc = 1.0f, br = 0.0f, bi = 0.0f;
        if (ag2 > 1e-24f) {
          float ag = sqrtf(ag2);
          float ta = (aqq - app) / (2.0f * ag);
          float tt = -copysignf(1.0f, ta) / (fabsf(ta) + sqrtf(1.0f + ta * ta));
          cc = 1.0f / sqrtf(1.0f + tt * tt);
          float tcag = tt * cc / ag;
          br = g.x * tcag; bi = g.y * tcag;
        }
        sprm[tid] = make_float4(cc, br, bi, __int_as_float(p | (q << 8)));
        Pg[r0 * 64 + tid] = make_float2(br, bi);
      }
      __syncthreads();   // params visible; all pre-round A reads done (WAR)
      for (int k = 0; k < nb; ++k) {
        float4 Pi = sprm[bi_[k]], Pj = sprm[bj_[k]];
        int pqi = __float_as_int(Pi.w), pqj = __float_as_int(Pj.w);
        int pi_ = pqi & 255, qi_ = pqi >> 8;
        int pj_ = pqj & 255, qj_ = pqj >> 8;
        float ci = Pi.x, bri = Pi.y, bii = Pi.z;
        float cj = Pj.x, brj = Pj.y, bij = Pj.z;
        float2 B00 = ldc(sAre, sAim, pi_, pj_);
        float2 B01 = ldc(sAre, sAim, pi_, qj_);
        float2 B10 = ldc(sAre, sAim, qi_, pj_);
        float2 B11 = ldc(sAre, sAim, qi_, qj_);
        // left: T = L_i * B
        float t00r = ci * B00.x + (bri * B10.x - bii * B10.y);
        float t00i = ci * B00.y + (bri * B10.y + bii * B10.x);
        float t01r = ci * B01.x + (bri * B11.x - bii * B11.y);
        float t01i = ci * B01.y + (bri * B11.y + bii * B11.x);
        float t10r = ci * B10.x - (bri * B00.x + bii * B00.y);
        float t10i = ci * B10.y - (bri * B00.y - bii * B00.x);
        float t11r = ci * B11.x - (bri * B01.x + bii * B01.y);
        float t11i = ci * B11.y - (bri * B01.y - bii * B01.x);
        // right: C = T * R_j
        stc(sAre, sAim, pi_, pj_,
            cj * t00r + (brj * t01r + bij * t01i),
            cj * t00i + (brj * t01i - bij * t01r));
        stc(sAre, sAim, pi_, qj_,
            cj * t01r - (brj * t00r - bij * t00i),
            cj * t01i - (brj * t00i + bij * t00r));
        stc(sAre, sAim, qi_, pj_,
            cj * t10r + (brj * t11r + bij * t11i),
            cj * t10i + (brj * t11i - bij * t11r));
        stc(sAre, sAim, qi_, qj_,
            cj * t11r - (brj * t10r - bij * t10i),
            cj * t11i - (brj * t10i + bij * t10r));
      }
      __syncthreads();   // RAW: writes visible before next round's reads
    }
    // publish sweep s params: the last __syncthreads drained every thread's
    // vmcnt -> all Pg stores are at least in L2; the release store performs
    // the agent-scope writeback so other XCDs see them.
    if (tid == 0) {
      __hip_atomic_store(&flags[b * SWEEPS + s], (unsigned)(it + 1),
                         __ATOMIC_RELEASE, __HIP_MEMORY_SCOPE_AGENT);
    }
  }

  // fused rankd (diag is canonical); A is NOT written back (dead after this)
  if (tid < NDIM) {
    float wj = sAre[tid * RS + tid];
    int rank = 0;
    for (int k2 = 0; k2 < NDIM; ++k2) {
      float wk = sAre[k2 * RS + k2];
      rank += (wk < wj) || (wk == wj && k2 < tid);
    }
    double mv = minv[(it * BATCH + b) * NDIM + rank];
    double v = (double)wj + mv;
    if (v < 0.0) v = 0.0;
    d1[b * NDIM + tid] = v;
    d2[b * NDIM + tid] = v - (double)wj;
  }
}

// Theta = V diag(d1) V^H ; Lamda = (1-e/r) Lamda + e * V diag(d2) V^H.
__global__ __launch_bounds__(256) void update_kernel(
    const float2* U, const double* d1, const double* d2,
    const float* rho, const float* eta, int it,
    double2* Theta, double2* Lamda) {
  __shared__ float ViRe[32][33], ViIm[32][33];
  __shared__ float VkRe[32][33], VkIm[32][33];
  __shared__ double s1[32], s2[32];
  int blk = blockIdx.x;
  int b = blk >> 4, tile = blk & 15, ti = tile >> 2, tk = tile & 3;
  int tid = threadIdx.x;
  int lk = tid & 31, lig = tid >> 5;
  double r = (double)rho[it], e = (double)eta[it];
  double a1x[4] = {0, 0, 0, 0}, a1y[4] = {0, 0, 0, 0};
  double a2x[4] = {0, 0, 0, 0}, a2y[4] = {0, 0, 0, 0};
  const float2* Ub = U + (size_t)b * NSQ;
  for (int jc = 0; jc < 4; ++jc) {
    for (int e2 = tid; e2 < 1024; e2 += 256) {
      int rr = e2 & 31, cc2 = e2 >> 5;
      float2 v1 = Ub[(jc * 32 + cc2) * NDIM + ti * 32 + rr];
      ViRe[rr][cc2] = v1.x; ViIm[rr][cc2] = v1.y;
      float2 v2 = Ub[(jc * 32 + cc2) * NDIM + tk * 32 + rr];
      VkRe[rr][cc2] = v2.x; VkIm[rr][cc2] = v2.y;
    }
    if (tid < 32) {
      s1[tid] = d1[b * NDIM + jc * 32 + tid];
      s2[tid] = d2[b * NDIM + jc * 32 + tid];
    }
    __syncthreads();
#pragma unroll
    for (int uo = 0; uo < 4; ++uo) {
      int li = lig + uo * 8;
      double ax = a1x[uo], ay = a1y[uo], bx = a2x[uo], by = a2y[uo];
      for (int jj = 0; jj < 32; ++jj) {
        float var = ViRe[li][jj], vai = ViIm[li][jj];
        float vbr = VkRe[lk][jj], vbi = VkIm[lk][jj];
        double pr = (double)(var * vbr + vai * vbi);
        double pi = (double)(vai * vbr - var * vbi);
        ax += s1[jj] * pr; ay += s1[jj] * pi;
        bx += s2[jj] * pr; by += s2[jj] * pi;
      }
      a1x[uo] = ax; a1y[uo] = ay; a2x[uo] = bx; a2y[uo] = by;
    }
    __syncthreads();
  }
  double lf = 1.0 - e / r;
#pragma unroll
  for (int uo = 0; uo < 4; ++uo) {
    int gi = ti * 32 + lig + uo * 8, gk = tk * 32 + lk;
    size_t idx = (size_t)b * NSQ + gi * NDIM + gk;
    Theta[idx] = make_double2(a1x[uo], a1y[uo]);
    double2 Lold = Lamda[idx];
    Lamda[idx] = make_double2(lf * Lold.x + e * a2x[uo], lf * Lold.y + e * a2y[uo]);
  }
}

// OUTPUT (float32 real parts): T[i][j] = u[|i-j|].re ; uvec.re = u.re
__global__ void writeout_kernel(const double2* u, float* out) {
  int tid = blockIdx.x * 256 + threadIdx.x;
  if (tid >= OUT_ELEMS) return;
  double re;
  if (tid < BATCH * MDIM * MDIM) {
    int b = tid >> 12, rem = tid & 4095, i = rem >> 6, j = rem & 63;
    int d = j - i;
    re = u[b * MDIM + (d >= 0 ? d : -d)].x;
  } else {
    int k2 = tid - BATCH * MDIM * MDIM;
    int b = k2 >> 6, kk = k2 & 63;
    re = u[b * MDIM + kk].x;
  }
  out[tid] = (float)re;
}

// ------------------------------- launch ------------------------------------
extern "C" void kernel_launch(void* const* d_in, const int* in_sizes, int n_in,
                              void* d_out, int out_size, void* d_ws, size_t ws_size,
                              hipStream_t stream) {
  const float* Yre = (const float*)d_in[0];
  const float* Yim = (const float*)d_in[1];
  const float* rho = (const float*)d_in[2];
  const float* tau = (const float*)d_in[3];
  const float* eta = (const float*)d_in[4];
  float* out = (float*)d_out;

  char* ws = (char*)d_ws;
  size_t off = 0;
  auto take = [&](size_t bytes) -> char* {
    char* p = ws + off;
    off += (bytes + 255) & ~(size_t)255;
    return p;
  };
  double2* u     = (double2*)take((size_t)BATCH * MDIM * sizeof(double2));
  double*  minv  = (double*)take((size_t)KITER * BATCH * NDIM * sizeof(double));
  double*  d1    = (double*)take((size_t)BATCH * NDIM * sizeof(double));
  double*  d2    = (double*)take((size_t)BATCH * NDIM * sizeof(double));
  double2* Lamda = (double2*)take((size_t)BATCH * NSQ * sizeof(double2));  // 16.8 MB
  double2* Theta = (double2*)take((size_t)BATCH * NSQ * sizeof(double2));  // 16.8 MB
  float2*  A32   = (float2*)take((size_t)BATCH * NSQ * sizeof(float2));    //  8.4 MB
  float2*  U32   = (float2*)take((size_t)BATCH * NSQ * sizeof(float2));    //  8.4 MB
  float2*  prm   = (float2*)take((size_t)SWEEPS * BATCH * 127 * 64 * sizeof(float2)); // 29.4 MB
  unsigned* flags = (unsigned*)take((size_t)BATCH * SWEEPS * sizeof(unsigned));
  (void)in_sizes; (void)n_in; (void)ws_size; (void)out_size;  // ~80.5 MB total

  hipFuncSetAttribute((const void*)combined_all_kernel,
                      hipFuncAttributeMaxDynamicSharedMemorySize, JAC_LDS_BYTES);

  zero_kernel<<<2048, 256, 0, stream>>>((double*)Theta, (size_t)BATCH * NSQ * 2);
  zero_kernel<<<2048, 256, 0, stream>>>((double*)Lamda, (size_t)BATCH * NSQ * 2);
  flags_zero_kernel<<<1, 512, 0, stream>>>(flags);
  prng_kernel<<<(KITER * BATCH * NDIM + 255) / 256, 256, 0, stream>>>(minv);

  for (int it = 0; it < KITER - 1; ++it) {
    compute_u_kernel<<<16, 256, 0, stream>>>(Theta, Lamda, rho, tau, it, u);
    assemble_kernel<<<BATCH * NSQ / 256, 256, 0, stream>>>(Theta, Lamda, u, Yre, Yim,
                                                           rho, tau, it, A32);
    combined_all_kernel<<<BATCH + 2 * BATCH, 512, JAC_LDS_BYTES, stream>>>(
        A32, U32, prm, flags, minv, it, d1, d2);
    update_kernel<<<BATCH * 16, 256, 0, stream>>>(U32, d1, d2, rho, eta, it, Theta, Lamda);
  }
  compute_u_kernel<<<16, 256, 0, stream>>>(Theta, Lamda, rho, tau, KITER - 1, u);
  writeout_kernel<<<(OUT_ELEMS + 255) / 256, 256, 0, stream>>>(u, out);
}

// Round 3
// 19828.809 us; speedup vs baseline: 1.2056x; 1.0949x over previous
//
#include <hip/hip_runtime.h>
#include <stdint.h>

// ---------------------------------------------------------------------------
// AnmNetwork: ADMM-like complex PSD iteration. B=64, m=l=64, n=128, K=10.
//  * Sita = V relu(w + minv[rank]) V^H  (second eigh mathematically redundant)
//  * Lamda_new = (1 - eta/rho) Lamda + eta * V diag(relu(w+m)-w) V^H
//  * Output depends only on state entering iteration K-1 -> 9 eigh rounds.
//  * PRNG: JAX threefry2x32 partitionable counters (bit-exact, R5).
// R15 = R14 (sweep fusion, one dispatch/iter, flags handoff) + LDS-issue cuts:
//  * A stored AoS float2 (stride 129 float2) -> every cell access is ONE
//    ds_read_b64/ds_write_b64 instead of two b32 (SoA). 64->32 LDS ops per
//    thread per round; bank-pair = (r+c) mod 16, consecutive lanes step c
//    -> ~4-way uniform = b64 data floor. (NOT R13's phase-split; the round
//    body keeps R12/R14's read-rotate-write-in-place structure.)
//  * Round barriers are lgkmcnt-only (asm + s_barrier, proven in R13):
//    wave0's per-round Pg global store stays in flight (no vmcnt(0) drain
//    per round); it drains once per sweep at the RELEASE atomic (same wave).
//  * Replay: RCH 12 (rows 16B-aligned) -> rotation via 16x ds_read/write_b128
//    instead of 64x b32; next-round params prefetched into regs (cross-XCD
//    global load latency hidden under rotation).
// State (Theta/Lamda), PRNG, u, writeout stay fp64. SWEEPS=7.
// ---------------------------------------------------------------------------

#define BATCH 64
#define MDIM 64
#define LDIM 64
#define NDIM 128
#define NSQ (NDIM * NDIM)
#define KITER 10
#define SWEEPS 7
#define RSA 129                                 // A row stride (float2 units)
#define JAC_LDS_BYTES (NDIM * RSA * (int)sizeof(float2))   // 132,096 B
#define RCH 12                                  // replay chunk col stride (dwords, 48B)
#define OUT_ELEMS 266240   // 64*64*64 (T) + 64*64 (uvec), f32 real parts

// ----------------------------- threefry2x32 --------------------------------
__device__ __forceinline__ void tf_block(unsigned k0, unsigned k1,
                                         unsigned& x0, unsigned& x1) {
  unsigned k2 = k0 ^ k1 ^ 0x1BD11BDAu;
  x0 += k0; x1 += k1;
#define TF_R(r) { x0 += x1; x1 = (x1 << (r)) | (x1 >> (32 - (r))); x1 ^= x0; }
  TF_R(13) TF_R(15) TF_R(26) TF_R(6)
  x0 += k1; x1 += k2 + 1u;
  TF_R(17) TF_R(29) TF_R(16) TF_R(24)
  x0 += k2; x1 += k0 + 2u;
  TF_R(13) TF_R(15) TF_R(26) TF_R(6)
  x0 += k0; x1 += k1 + 3u;
  TF_R(17) TF_R(29) TF_R(16) TF_R(24)
  x0 += k1; x1 += k2 + 4u;
  TF_R(13) TF_R(15) TF_R(26) TF_R(6)
  x0 += k2; x1 += k0 + 5u;
#undef TF_R
}

// ------------------------------- erfinv (f64) ------------------------------
__device__ double erfinv_d(double x) {
  double w = -log1p(-x * x);
  double p;
  if (w < 6.25) {
    w -= 3.125;
    const double c[23] = {
      -3.6444120640178196996e-21, -1.685059138182016589e-19,
      1.2858480715256400167e-18,  1.115787767802518096e-17,
      -1.333171662854620906e-16,  2.0972767875968561637e-17,
      6.6376381343583238325e-15,  -4.0545662729752068639e-14,
      -8.1519341976054721522e-14, 2.6335093153082322977e-12,
      -1.2975133253453532498e-11, -5.4154120542946279317e-11,
      1.051212273321532285e-09,   -4.1126339803469836976e-09,
      -2.9070369957882005086e-08, 4.2347877827932403518e-07,
      -1.3654692000834678645e-06, -1.3882523362786468719e-05,
      1.8673420803405714802e-04,  -7.4070253416626697512e-04,
      -6.0336708714301490533e-03, 2.4015818242558961693e-01,
      1.6536545626831027356e+00};
    p = c[0];
#pragma unroll
    for (int i = 1; i < 23; ++i) p = p * w + c[i];
  } else if (w < 16.0) {
    double s = sqrt(w) - 3.25;
    const double c[19] = {
      2.2137376921775787049e-09,  9.0756561938885390979e-08,
      -2.7517406297064545428e-07, 1.8239629214389227755e-08,
      1.5027403968909827627e-06,  -4.013867526981545969e-06,
      2.9234449089955446044e-06,  1.2475304481671778723e-05,
      -4.7318229009055733981e-05, 6.8284851459573175448e-05,
      2.4031110387097893999e-05,  -3.5503752036284748449e-04,
      9.5328937973738049703e-04,  -1.6882755560235047313e-03,
      2.4914420961078508066e-03,  -3.7512085075692412107e-03,
      5.3709145535900636051e-03,  1.0052589676941592334e+00,
      3.0838856104922207635e+00};
    p = c[0];
#pragma unroll
    for (int i = 1; i < 19; ++i) p = p * s + c[i];
  } else {
    double s = sqrt(w) - 5.0;
    const double c[17] = {
      -2.7109920616438573243e-11, -2.5556418169965252055e-10,
      1.5076572693500548083e-09,  -3.7894654401267369937e-09,
      7.6157012080783393804e-09,  -1.4960026627149240478e-08,
      2.9147953450901080826e-08,  -6.7711997758452339498e-08,
      2.2900482228026654717e-07,  -9.9298272942317002539e-07,
      4.5260625972231537039e-06,  -1.9681778105531670567e-05,
      7.5995277030017761139e-05,  -2.1503011930044477347e-04,
      -1.3871931833623122026e-04, 1.0103004648645343977e+00,
      4.8499064014085844221e+00};
    p = c[0];
#pragma unroll
    for (int i = 1; i < 17; ++i) p = p * s + c[i];
  }
  double z = p * x;
  const double spi2 = 0.8862269254527580;  // sqrt(pi)/2
  double ax = fabs(x);
#pragma unroll
  for (int nr = 0; nr < 2; ++nr) {
    if (ax > 0.9375) {
      double az = fabs(z);
      double corr = (erfc(az) - (1.0 - ax)) * spi2 * exp(az * az);
      az += corr;
      z = copysign(az, x);
    } else {
      z -= (erf(z) - x) * spi2 * exp(z * z);
    }
  }
  return z;
}

// ------------------------------- kernels -----------------------------------
__global__ void zero_kernel(double* p, size_t n) {
  size_t i = (size_t)blockIdx.x * blockDim.x + threadIdx.x;
  size_t stride = (size_t)gridDim.x * blockDim.x;
  for (; i < n; i += stride) p[i] = 0.0;
}

__global__ void flags_zero_kernel(unsigned* flags) {
  int tid = threadIdx.x;
  if (tid < BATCH * SWEEPS) flags[tid] = 0u;
}

__global__ void prng_kernel(double* minv) {
  int tid = blockIdx.x * blockDim.x + threadIdx.x;
  if (tid >= KITER * BATCH * NDIM) return;
  int it = tid / (BATCH * NDIM);
  int i = tid % (BATCH * NDIM);
  unsigned nk0 = 0u, nk1 = (unsigned)it;
  tf_block(0u, 42u, nk0, nk1);                       // fold_in
  unsigned c0 = 0u, c1 = (unsigned)i;                // partitionable counter
  tf_block(nk0, nk1, c0, c1);
  unsigned long long bits = ((unsigned long long)c0 << 32) | (unsigned long long)c1;
  unsigned long long fb = (bits >> 12) | 0x3FF0000000000000ull;
  double f = __builtin_bit_cast(double, fb) - 1.0;
  const double lo = __builtin_bit_cast(double, 0xBFEFFFFFFFFFFFFFull);
  double uu = f * 2.0 + lo;
  if (uu < lo) uu = lo;
  minv[tid] = 1.4142135623730951 * erfinv_d(uu);
}

__global__ void compute_u_kernel(const double2* Theta, const double2* Lamda,
                                 const float* rho, const float* tau, int it,
                                 double2* u) {
  int tid = blockIdx.x * blockDim.x + threadIdx.x;
  if (tid >= BATCH * MDIM) return;
  int b = tid / MDIM, kk = tid % MDIM;
  double r = (double)rho[it], t = (double)tau[it];
  const double2* Lb = Lamda + (size_t)b * NSQ;
  const double2* Tb = Theta + (size_t)b * NSQ;
  double ar = 0.0, ai = 0.0;
  for (int i = 0; i + kk < MDIM; ++i) {
    double2 L = Lb[i * NDIM + i + kk];
    double2 Th = Tb[i * NDIM + i + kk];
    ar += L.x + r * Th.x;
    ai += L.y + r * Th.y;
  }
  if (kk == 0) ar += -(t * 0.5) * (double)MDIM;
  double s = 1.0 / ((double)(MDIM - kk) * r);
  u[b * MDIM + kk] = make_double2(ar * s, ai * s);
}

// A32 = fp32(StackM - Lamda/r)   (U init lives in combined_all: U = I)
__global__ void assemble_kernel(const double2* Theta, const double2* Lamda,
                                const double2* u, const float* Yre, const float* Yim,
                                const float* rho, const float* tau, int it,
                                float2* A32) {
  int tid = blockIdx.x * 256 + threadIdx.x;
  if (tid >= BATCH * NSQ) return;
  int b = tid / NSQ, rem = tid % NSQ, i = rem / NDIM, j = rem % NDIM;
  double r = (double)rho[it], t = (double)tau[it];
  size_t idx = (size_t)b * NSQ + rem;
  double2 L = Lamda[idx], Th = Theta[idx];
  double axr, axi;
  if (i < MDIM && j < MDIM) {
    int d = j - i;
    double2 uv = u[b * MDIM + (d >= 0 ? d : -d)];
    double uy = (d >= 0) ? uv.y : -uv.y;
    axr = uv.x - L.x / r;
    axi = uy - L.y / r;
  } else if (i < MDIM) {
    double yr = (double)Yre[(b * MDIM + i) * LDIM + (j - MDIM)];
    double yi = (double)Yim[(b * MDIM + i) * LDIM + (j - MDIM)];
    double inv = 1.0 / (1.0 + 2.0 * r);
    axr = (yr + 2.0 * L.x + 2.0 * r * Th.x) * inv - L.x / r;
    axi = (yi + 2.0 * L.y + 2.0 * r * Th.y) * inv - L.y / r;
  } else if (j < MDIM) {
    double yr = (double)Yre[(b * MDIM + j) * LDIM + (i - MDIM)];
    double yi = -(double)Yim[(b * MDIM + j) * LDIM + (i - MDIM)];
    double inv = 1.0 / (1.0 + 2.0 * r);
    axr = (yr + 2.0 * L.x + 2.0 * r * Th.x) * inv - L.x / r;
    axi = (yi + 2.0 * L.y + 2.0 * r * Th.y) * inv - L.y / r;
  } else {
    axr = Th.x - ((i == j) ? t / (2.0 * r) : 0.0);
    axi = Th.y;
  }
  A32[idx] = make_float2((float)axr, (float)axi);
}

__device__ __forceinline__ int pair_p(int j, int r) {
  return (j == 0) ? 0 : 1 + (j - 1 + r) % 127;
}
__device__ __forceinline__ int pair_q(int j, int r) {
  return 1 + (126 - j + r) % 127;
}

// Canonical-upper accessors (AoS float2 plane, stride RSA) -> single b64 op.
__device__ __forceinline__ float2 ldc2(const float2* sA, int r, int c) {
  int rr = r <= c ? r : c, cc = r <= c ? c : r;
  float2 v = sA[rr * RSA + cc];
  if (r > c) v.y = -v.y;
  return v;
}
__device__ __forceinline__ void stc2(float2* sA, int r, int c, float zr, float zi) {
  int rr = r <= c ? r : c, cc = r <= c ? c : r;
  sA[rr * RSA + cc] = make_float2(zr, (r <= c) ? zi : -zi);
}

// Raw barrier: drain own LDS ops only -- wave0's Pg global stores stay in
// flight (drained once per sweep by the RELEASE atomic on the same wave).
__device__ __forceinline__ void bar_lgkm() {
  asm volatile("s_waitcnt lgkmcnt(0)" ::: "memory");
  __builtin_amdgcn_s_barrier();
}

// Fused dispatch: blocks 0..63 jacobi (all 7 sweeps, A LDS-resident, params
// released per sweep via device-scope flags); blocks 64..191 replay (U chunk
// LDS-resident across all 7 sweeps, init to I, acquire-spin per sweep).
__global__ __launch_bounds__(512) void combined_all_kernel(
    const float2* __restrict__ A, float2* __restrict__ U,
    float2* __restrict__ prm,        // [SWEEPS][BATCH][127][64]
    unsigned* __restrict__ flags,    // [BATCH][SWEEPS]
    const double* __restrict__ minv, int it,
    double* __restrict__ d1, double* __restrict__ d2) {
  extern __shared__ float smem[];
  int tid = threadIdx.x;

  if (blockIdx.x >= BATCH) {
    // ------------------------- replay path --------------------------------
    int rb = blockIdx.x - BATCH;
    int wv = tid >> 6, ln = tid & 63;
    int b = rb >> 1, half = rb & 1;
    int col0 = (half * 8 + wv) * 8;
    float* cre = smem + wv * (2 * NDIM * RCH);
    float* cim = cre + NDIM * RCH;
    // U = I (chunk init in LDS; no global load)
    for (int e = ln; e < NDIM * 8; e += 64) {
      int row = e >> 3, c = e & 7;
      cre[row * RCH + c] = (row == col0 + c) ? 1.0f : 0.0f;
      cim[row * RCH + c] = 0.0f;
    }
    for (int s = 0; s < SWEEPS; ++s) {
      const float2* Pg = prm + ((size_t)s * BATCH + b) * (127 * 64);
      if (ln == 0) {   // per-wave acquire spin (waves are independent)
        while (__hip_atomic_load(&flags[b * SWEEPS + s], __ATOMIC_ACQUIRE,
                                 __HIP_MEMORY_SCOPE_AGENT) != (unsigned)(it + 1)) {
          __builtin_amdgcn_s_sleep(8);
        }
      }
      // wave64 lockstep reconvergence: all lanes proceed after ln0's acquire
      float2 prmv = Pg[ln];   // round 0 params, prefetched
      for (int r0 = 0; r0 < 127; ++r0) {
        int r = (s & 1) ? (126 - r0) : r0;
        int p = pair_p(ln, r), q = pair_q(ln, r);
        float2 nxt = prmv;
        if (r0 < 126) nxt = Pg[(r0 + 1) * 64 + ln];   // prefetch next round
        float br = prmv.x, bi = prmv.y;
        float cc = sqrtf(fmaxf(0.0f, 1.0f - br * br - bi * bi));
        float4* Rp = (float4*)(cre + p * RCH);   // 48B rows: 16B-aligned
        float4* Rq = (float4*)(cre + q * RCH);
        float4* Ip = (float4*)(cim + p * RCH);
        float4* Iq = (float4*)(cim + q * RCH);
        float4 pr0 = Rp[0], pr1 = Rp[1], pim0 = Ip[0], pim1 = Ip[1];
        float4 qr0 = Rq[0], qr1 = Rq[1], qim0 = Iq[0], qim1 = Iq[1];
#define ROTC(UPX, UPY, UQX, UQY) { float upx = UPX, upy = UPY, uqx = UQX, uqy = UQY; \
    UPX = cc * upx + (br * uqx + bi * uqy);  /* U_p <- c U_p + conj(sb) U_q */       \
    UPY = cc * upy + (br * uqy - bi * uqx);                                          \
    UQX = cc * uqx - (br * upx - bi * upy);  /* U_q <- c U_q - sb U_p */             \
    UQY = cc * uqy - (br * upy + bi * upx); }
        ROTC(pr0.x, pim0.x, qr0.x, qim0.x)
        ROTC(pr0.y, pim0.y, qr0.y, qim0.y)
        ROTC(pr0.z, pim0.z, qr0.z, qim0.z)
        ROTC(pr0.w, pim0.w, qr0.w, qim0.w)
        ROTC(pr1.x, pim1.x, qr1.x, qim1.x)
        ROTC(pr1.y, pim1.y, qr1.y, qim1.y)
        ROTC(pr1.z, pim1.z, qr1.z, qim1.z)
        ROTC(pr1.w, pim1.w, qr1.w, qim1.w)
#undef ROTC
        Rp[0] = pr0; Rp[1] = pr1; Ip[0] = pim0; Ip[1] = pim1;
        Rq[0] = qr0; Rq[1] = qr1; Iq[0] = qim0; Iq[1] = qim1;
        prmv = nxt;
        __builtin_amdgcn_wave_barrier();
      }
    }
    float2* Ug = U + (size_t)b * NSQ;
    for (int e = ln; e < NDIM * 8; e += 64) {
      int row = e >> 3, c = e & 7;
      Ug[row * NDIM + col0 + c] = make_float2(cre[row * RCH + c], cim[row * RCH + c]);
    }
    return;
  }

  // --------------------------- jacobi path --------------------------------
  float2* sA2 = (float2*)smem;    // 128 x 129 float2 (AoS re,im)
  __shared__ float4 sprm[64];     // {c, br, bi, bitcast(p | q<<8)}
  int b = blockIdx.x;
  const float2* Ag = A + (size_t)b * NSQ;
  for (int i = tid; i < NSQ; i += 512) {
    sA2[(i >> 7) * RSA + (i & 127)] = Ag[i];
  }
  // decode this thread's canonical slot-pair blocks (i<=j), fixed all rounds
  int nb = (tid >= 480) ? 5 : 4;
  int bi_[5], bj_[5];
#pragma unroll
  for (int k = 0; k < 4; ++k) {
    int e = tid + 512 * k;
    int i = 0;
    while (i < 63 && (64 * (i + 1) - ((i + 1) * i) / 2) <= e) ++i;
    bi_[k] = i;
    bj_[k] = i + (e - (64 * i - (i * (i - 1)) / 2));
  }
  if (nb == 5) {
    int e = 2048 + (tid - 480);
    int i = 0;
    while (i < 63 && (64 * (i + 1) - ((i + 1) * i) / 2) <= e) ++i;
    bi_[4] = i;
    bj_[4] = i + (e - (64 * i - (i * (i - 1)) / 2));
  }
  __syncthreads();

  for (int s = 0; s < SWEEPS; ++s) {
    float2* Pg = prm + ((size_t)s * BATCH + b) * (127 * 64);
    for (int r0 = 0; r0 < 127; ++r0) {
      int r = (s & 1) ? (126 - r0) : r0;
      if (tid < 64) {
        int p = pair_p(tid, r), q = pair_q(tid, r);
        float app = sA2[p * RSA + p].x, aqq = sA2[q * RSA + q].x;
        float2 g = ldc2(sA2, p, q);
        float ag2 = g.x * g.x + g.y * g.y;
        float cc = 1.0f, br = 0.0f, bi = 0.0f;
        if (ag2 > 1e-24f) {
          float ag = sqrtf(ag2);
          float ta = (aqq - app) / (2.0f * ag);
          float tt = -copysignf(1.0f, ta) / (fabsf(ta) + sqrtf(1.0f + ta * ta));
          cc = 1.0f / sqrtf(1.0f + tt * tt);
          float tcag = tt * cc / ag;
          br = g.x * tcag; bi = g.y * tcag;
        }
        sprm[tid] = make_float4(cc, br, bi, __int_as_float(p | (q << 8)));
        Pg[r0 * 64 + tid] = make_float2(br, bi);   // fire-and-forget (no vmcnt)
      }
      bar_lgkm();   // params visible; all pre-round A reads done (WAR)
      for (int k = 0; k < nb; ++k) {
        float4 Pi = sprm[bi_[k]], Pj = sprm[bj_[k]];
        int pqi = __float_as_int(Pi.w), pqj = __float_as_int(Pj.w);
        int pi_ = pqi & 255, qi_ = pqi >> 8;
        int pj_ = pqj & 255, qj_ = pqj >> 8;
        float ci = Pi.x, bri = Pi.y, bii = Pi.z;
        float cj = Pj.x, brj = Pj.y, bij = Pj.z;
        float2 B00 = ldc2(sA2, pi_, pj_);
        float2 B01 = ldc2(sA2, pi_, qj_);
        float2 B10 = ldc2(sA2, qi_, pj_);
        float2 B11 = ldc2(sA2, qi_, qj_);
        // left: T = L_i * B
        float t00r = ci * B00.x + (bri * B10.x - bii * B10.y);
        float t00i = ci * B00.y + (bri * B10.y + bii * B10.x);
        float t01r = ci * B01.x + (bri * B11.x - bii * B11.y);
        float t01i = ci * B01.y + (bri * B11.y + bii * B11.x);
        float t10r = ci * B10.x - (bri * B00.x + bii * B00.y);
        float t10i = ci * B10.y - (bri * B00.y - bii * B00.x);
        float t11r = ci * B11.x - (bri * B01.x + bii * B01.y);
        float t11i = ci * B11.y - (bri * B01.y - bii * B01.x);
        // right: C = T * R_j
        stc2(sA2, pi_, pj_,
             cj * t00r + (brj * t01r + bij * t01i),
             cj * t00i + (brj * t01i - bij * t01r));
        stc2(sA2, pi_, qj_,
             cj * t01r - (brj * t00r - bij * t00i),
             cj * t01i - (brj * t00i + bij * t00r));
        stc2(sA2, qi_, pj_,
             cj * t10r + (brj * t11r + bij * t11i),
             cj * t10i + (brj * t11i - bij * t11r));
        stc2(sA2, qi_, qj_,
             cj * t11r - (brj * t10r - bij * t10i),
             cj * t11i - (brj * t10i + bij * t10r));
      }
      bar_lgkm();   // RAW: writes visible before next round's reads
    }
    // publish sweep s params: RELEASE drains wave0's outstanding Pg stores
    // (all issued by wave 0) and performs agent-scope writeback.
    if (tid == 0) {
      __hip_atomic_store(&flags[b * SWEEPS + s], (unsigned)(it + 1),
                         __ATOMIC_RELEASE, __HIP_MEMORY_SCOPE_AGENT);
    }
  }

  // fused rankd (diag is canonical); A is NOT written back (dead after this)
  if (tid < NDIM) {
    float wj = sA2[tid * RSA + tid].x;
    int rank = 0;
    for (int k2 = 0; k2 < NDIM; ++k2) {
      float wk = sA2[k2 * RSA + k2].x;
      rank += (wk < wj) || (wk == wj && k2 < tid);
    }
    double mv = minv[(it * BATCH + b) * NDIM + rank];
    double v = (double)wj + mv;
    if (v < 0.0) v = 0.0;
    d1[b * NDIM + tid] = v;
    d2[b * NDIM + tid] = v - (double)wj;
  }
}

// Theta = V diag(d1) V^H ; Lamda = (1-e/r) Lamda + e * V diag(d2) V^H.
__global__ __launch_bounds__(256) void update_kernel(
    const float2* U, const double* d1, const double* d2,
    const float* rho, const float* eta, int it,
    double2* Theta, double2* Lamda) {
  __shared__ float ViRe[32][33], ViIm[32][33];
  __shared__ float VkRe[32][33], VkIm[32][33];
  __shared__ double s1[32], s2[32];
  int blk = blockIdx.x;
  int b = blk >> 4, tile = blk & 15, ti = tile >> 2, tk = tile & 3;
  int tid = threadIdx.x;
  int lk = tid & 31, lig = tid >> 5;
  double r = (double)rho[it], e = (double)eta[it];
  double a1x[4] = {0, 0, 0, 0}, a1y[4] = {0, 0, 0, 0};
  double a2x[4] = {0, 0, 0, 0}, a2y[4] = {0, 0, 0, 0};
  const float2* Ub = U + (size_t)b * NSQ;
  for (int jc = 0; jc < 4; ++jc) {
    for (int e2 = tid; e2 < 1024; e2 += 256) {
      int rr = e2 & 31, cc2 = e2 >> 5;
      float2 v1 = Ub[(jc * 32 + cc2) * NDIM + ti * 32 + rr];
      ViRe[rr][cc2] = v1.x; ViIm[rr][cc2] = v1.y;
      float2 v2 = Ub[(jc * 32 + cc2) * NDIM + tk * 32 + rr];
      VkRe[rr][cc2] = v2.x; VkIm[rr][cc2] = v2.y;
    }
    if (tid < 32) {
      s1[tid] = d1[b * NDIM + jc * 32 + tid];
      s2[tid] = d2[b * NDIM + jc * 32 + tid];
    }
    __syncthreads();
#pragma unroll
    for (int uo = 0; uo < 4; ++uo) {
      int li = lig + uo * 8;
      double ax = a1x[uo], ay = a1y[uo], bx = a2x[uo], by = a2y[uo];
      for (int jj = 0; jj < 32; ++jj) {
        float var = ViRe[li][jj], vai = ViIm[li][jj];
        float vbr = VkRe[lk][jj], vbi = VkIm[lk][jj];
        double pr = (double)(var * vbr + vai * vbi);
        double pi = (double)(vai * vbr - var * vbi);
        ax += s1[jj] * pr; ay += s1[jj] * pi;
        bx += s2[jj] * pr; by += s2[jj] * pi;
      }
      a1x[uo] = ax; a1y[uo] = ay; a2x[uo] = bx; a2y[uo] = by;
    }
    __syncthreads();
  }
  double lf = 1.0 - e / r;
#pragma unroll
  for (int uo = 0; uo < 4; ++uo) {
    int gi = ti * 32 + lig + uo * 8, gk = tk * 32 + lk;
    size_t idx = (size_t)b * NSQ + gi * NDIM + gk;
    Theta[idx] = make_double2(a1x[uo], a1y[uo]);
    double2 Lold = Lamda[idx];
    Lamda[idx] = make_double2(lf * Lold.x + e * a2x[uo], lf * Lold.y + e * a2y[uo]);
  }
}

// OUTPUT (float32 real parts): T[i][j] = u[|i-j|].re ; uvec.re = u.re
__global__ void writeout_kernel(const double2* u, float* out) {
  int tid = blockIdx.x * 256 + threadIdx.x;
  if (tid >= OUT_ELEMS) return;
  double re;
  if (tid < BATCH * MDIM * MDIM) {
    int b = tid >> 12, rem = tid & 4095, i = rem >> 6, j = rem & 63;
    int d = j - i;
    re = u[b * MDIM + (d >= 0 ? d : -d)].x;
  } else {
    int k2 = tid - BATCH * MDIM * MDIM;
    int b = k2 >> 6, kk = k2 & 63;
    re = u[b * MDIM + kk].x;
  }
  out[tid] = (float)re;
}

// ------------------------------- launch ------------------------------------
extern "C" void kernel_launch(void* const* d_in, const int* in_sizes, int n_in,
                              void* d_out, int out_size, void* d_ws, size_t ws_size,
                              hipStream_t stream) {
  const float* Yre = (const float*)d_in[0];
  const float* Yim = (const float*)d_in[1];
  const float* rho = (const float*)d_in[2];
  const float* tau = (const float*)d_in[3];
  const float* eta = (const float*)d_in[4];
  float* out = (float*)d_out;

  char* ws = (char*)d_ws;
  size_t off = 0;
  auto take = [&](size_t bytes) -> char* {
    char* p = ws + off;
    off += (bytes + 255) & ~(size_t)255;
    return p;
  };
  double2* u     = (double2*)take((size_t)BATCH * MDIM * sizeof(double2));
  double*  minv  = (double*)take((size_t)KITER * BATCH * NDIM * sizeof(double));
  double*  d1    = (double*)take((size_t)BATCH * NDIM * sizeof(double));
  double*  d2    = (double*)take((size_t)BATCH * NDIM * sizeof(double));
  double2* Lamda = (double2*)take((size_t)BATCH * NSQ * sizeof(double2));  // 16.8 MB
  double2* Theta = (double2*)take((size_t)BATCH * NSQ * sizeof(double2));  // 16.8 MB
  float2*  A32   = (float2*)take((size_t)BATCH * NSQ * sizeof(float2));    //  8.4 MB
  float2*  U32   = (float2*)take((size_t)BATCH * NSQ * sizeof(float2));    //  8.4 MB
  float2*  prm   = (float2*)take((size_t)SWEEPS * BATCH * 127 * 64 * sizeof(float2)); // 29.4 MB
  unsigned* flags = (unsigned*)take((size_t)BATCH * SWEEPS * sizeof(unsigned));
  (void)in_sizes; (void)n_in; (void)ws_size; (void)out_size;  // ~80.5 MB total

  hipFuncSetAttribute((const void*)combined_all_kernel,
                      hipFuncAttributeMaxDynamicSharedMemorySize, JAC_LDS_BYTES);

  zero_kernel<<<2048, 256, 0, stream>>>((double*)Theta, (size_t)BATCH * NSQ * 2);
  zero_kernel<<<2048, 256, 0, stream>>>((double*)Lamda, (size_t)BATCH * NSQ * 2);
  flags_zero_kernel<<<1, 512, 0, stream>>>(flags);
  prng_kernel<<<(KITER * BATCH * NDIM + 255) / 256, 256, 0, stream>>>(minv);

  for (int it = 0; it < KITER - 1; ++it) {
    compute_u_kernel<<<16, 256, 0, stream>>>(Theta, Lamda, rho, tau, it, u);
    assemble_kernel<<<BATCH * NSQ / 256, 256, 0, stream>>>(Theta, Lamda, u, Yre, Yim,
                                                           rho, tau, it, A32);
    combined_all_kernel<<<BATCH + 2 * BATCH, 512, JAC_LDS_BYTES, stream>>>(
        A32, U32, prm, flags, minv, it, d1, d2);
    update_kernel<<<BATCH * 16, 0 * 0 + 256, 0, stream>>>(U32, d1, d2, rho, eta, it, Theta, Lamda);
  }
  compute_u_kernel<<<16, 256, 0, stream>>>(Theta, Lamda, rho, tau, KITER - 1, u);
  writeout_kernel<<<(OUT_ELEMS + 255) / 256, 256, 0, stream>>>(u, out);
}

// Round 4
// 18726.343 us; speedup vs baseline: 1.2766x; 1.0589x over previous
//
#include <hip/hip_runtime.h>
#include <stdint.h>

// ---------------------------------------------------------------------------
// AnmNetwork: ADMM-like complex PSD iteration. B=64, m=l=64, n=128, K=10.
//  * Sita = V relu(w + minv[rank]) V^H  (second eigh mathematically redundant)
//  * Lamda_new = (1 - eta/rho) Lamda + eta * V diag(relu(w+m)-w) V^H
//  * Output depends only on state entering iteration K-1 -> 9 eigh rounds.
//  * PRNG: JAX threefry2x32 partitionable counters (bit-exact, R5).
// R16 = R15 (sweep fusion + AoS b64 cells + lgkm barriers) + LATENCY attack
// (R15 post-mortem: bank conflicts now trivial; round is latency/serial
// bound at 2 waves/SIMD, sprm.w -> address dependency, serial wave0):
//  * 1024 threads/block (16 waves, 4/SIMD): per-thread phase B halves,
//    doubled wave parallelism hides ds_read->VALU chains. Same total LDS
//    and VALU work per CU.
//  * Register (p,q) trackers (R13's verified wrap-increment, WITHOUT its
//    failed phase-split): B-cell addresses independent of the sprm read ->
//    all b64 reads issue at phase-B start; sprm b128 in parallel.
//  * Wave 0 owns ZERO phase-B blocks (params only); 2080 blocks over
//    threads 64..1023 (>=864 take 3) -> waves finish rounds together.
//  * Replay blocks: threads >=512 exit (no block barriers on that path).
// State (Theta/Lamda), PRNG, u, writeout stay fp64. SWEEPS=7.
// ---------------------------------------------------------------------------

#define BATCH 64
#define MDIM 64
#define LDIM 64
#define NDIM 128
#define NSQ (NDIM * NDIM)
#define KITER 10
#define SWEEPS 7
#define RSA 129                                 // A row stride (float2 units)
#define JAC_LDS_BYTES (NDIM * RSA * (int)sizeof(float2))   // 132,096 B
#define RCH 12                                  // replay chunk col stride (dwords, 48B)
#define OUT_ELEMS 266240   // 64*64*64 (T) + 64*64 (uvec), f32 real parts

// ----------------------------- threefry2x32 --------------------------------
__device__ __forceinline__ void tf_block(unsigned k0, unsigned k1,
                                         unsigned& x0, unsigned& x1) {
  unsigned k2 = k0 ^ k1 ^ 0x1BD11BDAu;
  x0 += k0; x1 += k1;
#define TF_R(r) { x0 += x1; x1 = (x1 << (r)) | (x1 >> (32 - (r))); x1 ^= x0; }
  TF_R(13) TF_R(15) TF_R(26) TF_R(6)
  x0 += k1; x1 += k2 + 1u;
  TF_R(17) TF_R(29) TF_R(16) TF_R(24)
  x0 += k2; x1 += k0 + 2u;
  TF_R(13) TF_R(15) TF_R(26) TF_R(6)
  x0 += k0; x1 += k1 + 3u;
  TF_R(17) TF_R(29) TF_R(16) TF_R(24)
  x0 += k1; x1 += k2 + 4u;
  TF_R(13) TF_R(15) TF_R(26) TF_R(6)
  x0 += k2; x1 += k0 + 5u;
#undef TF_R
}

// ------------------------------- erfinv (f64) ------------------------------
__device__ double erfinv_d(double x) {
  double w = -log1p(-x * x);
  double p;
  if (w < 6.25) {
    w -= 3.125;
    const double c[23] = {
      -3.6444120640178196996e-21, -1.685059138182016589e-19,
      1.2858480715256400167e-18,  1.115787767802518096e-17,
      -1.333171662854620906e-16,  2.0972767875968561637e-17,
      6.6376381343583238325e-15,  -4.0545662729752068639e-14,
      -8.1519341976054721522e-14, 2.6335093153082322977e-12,
      -1.2975133253453532498e-11, -5.4154120542946279317e-11,
      1.051212273321532285e-09,   -4.1126339803469836976e-09,
      -2.9070369957882005086e-08, 4.2347877827932403518e-07,
      -1.3654692000834678645e-06, -1.3882523362786468719e-05,
      1.8673420803405714802e-04,  -7.4070253416626697512e-04,
      -6.0336708714301490533e-03, 2.4015818242558961693e-01,
      1.6536545626831027356e+00};
    p = c[0];
#pragma unroll
    for (int i = 1; i < 23; ++i) p = p * w + c[i];
  } else if (w < 16.0) {
    double s = sqrt(w) - 3.25;
    const double c[19] = {
      2.2137376921775787049e-09,  9.0756561938885390979e-08,
      -2.7517406297064545428e-07, 1.8239629214389227755e-08,
      1.5027403968909827627e-06,  -4.013867526981545969e-06,
      2.9234449089955446044e-06,  1.2475304481671778723e-05,
      -4.7318229009055733981e-05, 6.8284851459573175448e-05,
      2.4031110387097893999e-05,  -3.5503752036284748449e-04,
      9.5328937973738049703e-04,  -1.6882755560235047313e-03,
      2.4914420961078508066e-03,  -3.7512085075692412107e-03,
      5.3709145535900636051e-03,  1.0052589676941592334e+00,
      3.0838856104922207635e+00};
    p = c[0];
#pragma unroll
    for (int i = 1; i < 19; ++i) p = p * s + c[i];
  } else {
    double s = sqrt(w) - 5.0;
    const double c[17] = {
      -2.7109920616438573243e-11, -2.5556418169965252055e-10,
      1.5076572693500548083e-09,  -3.7894654401267369937e-09,
      7.6157012080783393804e-09,  -1.4960026627149240478e-08,
      2.9147953450901080826e-08,  -6.7711997758452339498e-08,
      2.2900482228026654717e-07,  -9.9298272942317002539e-07,
      4.5260625972231537039e-06,  -1.9681778105531670567e-05,
      7.5995277030017761139e-05,  -2.1503011930044477347e-04,
      -1.3871931833623122026e-04, 1.0103004648645343977e+00,
      4.8499064014085844221e+00};
    p = c[0];
#pragma unroll
    for (int i = 1; i < 17; ++i) p = p * s + c[i];
  }
  double z = p * x;
  const double spi2 = 0.8862269254527580;  // sqrt(pi)/2
  double ax = fabs(x);
#pragma unroll
  for (int nr = 0; nr < 2; ++nr) {
    if (ax > 0.9375) {
      double az = fabs(z);
      double corr = (erfc(az) - (1.0 - ax)) * spi2 * exp(az * az);
      az += corr;
      z = copysign(az, x);
    } else {
      z -= (erf(z) - x) * spi2 * exp(z * z);
    }
  }
  return z;
}

// ------------------------------- kernels -----------------------------------
__global__ void zero_kernel(double* p, size_t n) {
  size_t i = (size_t)blockIdx.x * blockDim.x + threadIdx.x;
  size_t stride = (size_t)gridDim.x * blockDim.x;
  for (; i < n; i += stride) p[i] = 0.0;
}

__global__ void flags_zero_kernel(unsigned* flags) {
  int tid = threadIdx.x;
  if (tid < BATCH * SWEEPS) flags[tid] = 0u;
}

__global__ void prng_kernel(double* minv) {
  int tid = blockIdx.x * blockDim.x + threadIdx.x;
  if (tid >= KITER * BATCH * NDIM) return;
  int it = tid / (BATCH * NDIM);
  int i = tid % (BATCH * NDIM);
  unsigned nk0 = 0u, nk1 = (unsigned)it;
  tf_block(0u, 42u, nk0, nk1);                       // fold_in
  unsigned c0 = 0u, c1 = (unsigned)i;                // partitionable counter
  tf_block(nk0, nk1, c0, c1);
  unsigned long long bits = ((unsigned long long)c0 << 32) | (unsigned long long)c1;
  unsigned long long fb = (bits >> 12) | 0x3FF0000000000000ull;
  double f = __builtin_bit_cast(double, fb) - 1.0;
  const double lo = __builtin_bit_cast(double, 0xBFEFFFFFFFFFFFFFull);
  double uu = f * 2.0 + lo;
  if (uu < lo) uu = lo;
  minv[tid] = 1.4142135623730951 * erfinv_d(uu);
}

__global__ void compute_u_kernel(const double2* Theta, const double2* Lamda,
                                 const float* rho, const float* tau, int it,
                                 double2* u) {
  int tid = blockIdx.x * blockDim.x + threadIdx.x;
  if (tid >= BATCH * MDIM) return;
  int b = tid / MDIM, kk = tid % MDIM;
  double r = (double)rho[it], t = (double)tau[it];
  const double2* Lb = Lamda + (size_t)b * NSQ;
  const double2* Tb = Theta + (size_t)b * NSQ;
  double ar = 0.0, ai = 0.0;
  for (int i = 0; i + kk < MDIM; ++i) {
    double2 L = Lb[i * NDIM + i + kk];
    double2 Th = Tb[i * NDIM + i + kk];
    ar += L.x + r * Th.x;
    ai += L.y + r * Th.y;
  }
  if (kk == 0) ar += -(t * 0.5) * (double)MDIM;
  double s = 1.0 / ((double)(MDIM - kk) * r);
  u[b * MDIM + kk] = make_double2(ar * s, ai * s);
}

// A32 = fp32(StackM - Lamda/r)   (U init lives in combined_all: U = I)
__global__ void assemble_kernel(const double2* Theta, const double2* Lamda,
                                const double2* u, const float* Yre, const float* Yim,
                                const float* rho, const float* tau, int it,
                                float2* A32) {
  int tid = blockIdx.x * 256 + threadIdx.x;
  if (tid >= BATCH * NSQ) return;
  int b = tid / NSQ, rem = tid % NSQ, i = rem / NDIM, j = rem % NDIM;
  double r = (double)rho[it], t = (double)tau[it];
  size_t idx = (size_t)b * NSQ + rem;
  double2 L = Lamda[idx], Th = Theta[idx];
  double axr, axi;
  if (i < MDIM && j < MDIM) {
    int d = j - i;
    double2 uv = u[b * MDIM + (d >= 0 ? d : -d)];
    double uy = (d >= 0) ? uv.y : -uv.y;
    axr = uv.x - L.x / r;
    axi = uy - L.y / r;
  } else if (i < MDIM) {
    double yr = (double)Yre[(b * MDIM + i) * LDIM + (j - MDIM)];
    double yi = (double)Yim[(b * MDIM + i) * LDIM + (j - MDIM)];
    double inv = 1.0 / (1.0 + 2.0 * r);
    axr = (yr + 2.0 * L.x + 2.0 * r * Th.x) * inv - L.x / r;
    axi = (yi + 2.0 * L.y + 2.0 * r * Th.y) * inv - L.y / r;
  } else if (j < MDIM) {
    double yr = (double)Yre[(b * MDIM + j) * LDIM + (i - MDIM)];
    double yi = -(double)Yim[(b * MDIM + j) * LDIM + (i - MDIM)];
    double inv = 1.0 / (1.0 + 2.0 * r);
    axr = (yr + 2.0 * L.x + 2.0 * r * Th.x) * inv - L.x / r;
    axi = (yi + 2.0 * L.y + 2.0 * r * Th.y) * inv - L.y / r;
  } else {
    axr = Th.x - ((i == j) ? t / (2.0 * r) : 0.0);
    axi = Th.y;
  }
  A32[idx] = make_float2((float)axr, (float)axi);
}

__device__ __forceinline__ int pair_p(int j, int r) {
  return (j == 0) ? 0 : 1 + (j - 1 + r) % 127;
}
__device__ __forceinline__ int pair_q(int j, int r) {
  return 1 + (126 - j + r) % 127;
}

// Canonical-upper accessors (AoS float2 plane, stride RSA) -> single b64 op.
__device__ __forceinline__ float2 ldc2(const float2* sA, int r, int c) {
  int rr = r <= c ? r : c, cc = r <= c ? c : r;
  float2 v = sA[rr * RSA + cc];
  if (r > c) v.y = -v.y;
  return v;
}
__device__ __forceinline__ void stc2(float2* sA, int r, int c, float zr, float zi) {
  int rr = r <= c ? r : c, cc = r <= c ? c : r;
  sA[rr * RSA + cc] = make_float2(zr, (r <= c) ? zi : -zi);
}

// Raw barrier: drain own LDS ops only -- wave0's Pg global stores stay in
// flight (drained once per sweep by the RELEASE atomic on the same wave).
__device__ __forceinline__ void bar_lgkm() {
  asm volatile("s_waitcnt lgkmcnt(0)" ::: "memory");
  __builtin_amdgcn_s_barrier();
}

// Fused dispatch: blocks 0..63 jacobi (all 7 sweeps, A LDS-resident, params
// released per sweep via device-scope flags); blocks 64..191 replay (U chunk
// LDS-resident across all 7 sweeps, init to I, acquire-spin per sweep).
__global__ __launch_bounds__(1024) void combined_all_kernel(
    const float2* __restrict__ A, float2* __restrict__ U,
    float2* __restrict__ prm,        // [SWEEPS][BATCH][127][64]
    unsigned* __restrict__ flags,    // [BATCH][SWEEPS]
    const double* __restrict__ minv, int it,
    double* __restrict__ d1, double* __restrict__ d2) {
  extern __shared__ float smem[];
  int tid = threadIdx.x;

  if (blockIdx.x >= BATCH) {
    // ------------------------- replay path --------------------------------
    if (tid >= 512) return;   // 8 working waves; no block barriers here
    int rb = blockIdx.x - BATCH;
    int wv = tid >> 6, ln = tid & 63;
    int b = rb >> 1, half = rb & 1;
    int col0 = (half * 8 + wv) * 8;
    float* cre = smem + wv * (2 * NDIM * RCH);
    float* cim = cre + NDIM * RCH;
    // U = I (chunk init in LDS; no global load)
    for (int e = ln; e < NDIM * 8; e += 64) {
      int row = e >> 3, c = e & 7;
      cre[row * RCH + c] = (row == col0 + c) ? 1.0f : 0.0f;
      cim[row * RCH + c] = 0.0f;
    }
    for (int s = 0; s < SWEEPS; ++s) {
      const float2* Pg = prm + ((size_t)s * BATCH + b) * (127 * 64);
      if (ln == 0) {   // per-wave acquire spin (waves are independent)
        while (__hip_atomic_load(&flags[b * SWEEPS + s], __ATOMIC_ACQUIRE,
                                 __HIP_MEMORY_SCOPE_AGENT) != (unsigned)(it + 1)) {
          __builtin_amdgcn_s_sleep(8);
        }
      }
      // wave64 lockstep reconvergence: all lanes proceed after ln0's acquire
      float2 prmv = Pg[ln];   // round 0 params, prefetched
      for (int r0 = 0; r0 < 127; ++r0) {
        int r = (s & 1) ? (126 - r0) : r0;
        int p = pair_p(ln, r), q = pair_q(ln, r);
        float2 nxt = prmv;
        if (r0 < 126) nxt = Pg[(r0 + 1) * 64 + ln];   // prefetch next round
        float br = prmv.x, bi = prmv.y;
        float cc = sqrtf(fmaxf(0.0f, 1.0f - br * br - bi * bi));
        float4* Rp = (float4*)(cre + p * RCH);   // 48B rows: 16B-aligned
        float4* Rq = (float4*)(cre + q * RCH);
        float4* Ip = (float4*)(cim + p * RCH);
        float4* Iq = (float4*)(cim + q * RCH);
        float4 pr0 = Rp[0], pr1 = Rp[1], pim0 = Ip[0], pim1 = Ip[1];
        float4 qr0 = Rq[0], qr1 = Rq[1], qim0 = Iq[0], qim1 = Iq[1];
#define ROTC(UPX, UPY, UQX, UQY) { float upx = UPX, upy = UPY, uqx = UQX, uqy = UQY; \
    UPX = cc * upx + (br * uqx + bi * uqy);  /* U_p <- c U_p + conj(sb) U_q */       \
    UPY = cc * upy + (br * uqy - bi * uqx);                                          \
    UQX = cc * uqx - (br * upx - bi * upy);  /* U_q <- c U_q - sb U_p */             \
    UQY = cc * uqy - (br * upy + bi * upx); }
        ROTC(pr0.x, pim0.x, qr0.x, qim0.x)
        ROTC(pr0.y, pim0.y, qr0.y, qim0.y)
        ROTC(pr0.z, pim0.z, qr0.z, qim0.z)
        ROTC(pr0.w, pim0.w, qr0.w, qim0.w)
        ROTC(pr1.x, pim1.x, qr1.x, qim1.x)
        ROTC(pr1.y, pim1.y, qr1.y, qim1.y)
        ROTC(pr1.z, pim1.z, qr1.z, qim1.z)
        ROTC(pr1.w, pim1.w, qr1.w, qim1.w)
#undef ROTC
        Rp[0] = pr0; Rp[1] = pr1; Ip[0] = pim0; Ip[1] = pim1;
        Rq[0] = qr0; Rq[1] = qr1; Iq[0] = qim0; Iq[1] = qim1;
        prmv = nxt;
        __builtin_amdgcn_wave_barrier();
      }
    }
    float2* Ug = U + (size_t)b * NSQ;
    for (int e = ln; e < NDIM * 8; e += 64) {
      int row = e >> 3, c = e & 7;
      Ug[row * NDIM + col0 + c] = make_float2(cre[row * RCH + c], cim[row * RCH + c]);
    }
    return;
  }

  // --------------------------- jacobi path --------------------------------
  // 1024 threads: wave 0 (tid<64) does params only; threads 64..1023 own
  // the 2080 canonical slot-pair blocks (tid>=864 take 3, else 2).
  float2* sA2 = (float2*)smem;    // 128 x 129 float2 (AoS re,im)
  __shared__ float4 sprm[64];     // {c, br, bi, 0}
  int b = blockIdx.x;
  const float2* Ag = A + (size_t)b * NSQ;
  for (int i = tid; i < NSQ; i += 1024) {
    sA2[(i >> 7) * RSA + (i & 127)] = Ag[i];
  }
  int nb = 0;
  int bi_[3], bj_[3];
  bi_[0] = bi_[1] = bi_[2] = 0; bj_[0] = bj_[1] = bj_[2] = 0;
  if (tid >= 64) {
    nb = (tid >= 864) ? 3 : 2;
#pragma unroll
    for (int k = 0; k < 3; ++k) {
      if (k >= nb) break;
      int e = (k < 2) ? ((tid - 64) + 960 * k) : (1920 + (tid - 864));
      int i = 0;
      while (i < 63 && (64 * (i + 1) - ((i + 1) * i) / 2) <= e) ++i;
      bi_[k] = i;
      bj_[k] = i + (e - (64 * i - (i * (i - 1)) / 2));
    }
  }
  __syncthreads();

  for (int s = 0; s < SWEEPS; ++s) {
    float2* Pg = prm + ((size_t)s * BATCH + b) * (127 * 64);
    const bool fwd = !(s & 1);
    const int r_init = fwd ? 0 : 126;
    // register slot->row trackers (addresses independent of sprm read)
    int pi_[3], qi_[3], pj_[3], qj_[3];
#pragma unroll
    for (int k = 0; k < 3; ++k) {
      pi_[k] = pair_p(bi_[k], r_init); qi_[k] = pair_q(bi_[k], r_init);
      pj_[k] = pair_p(bj_[k], r_init); qj_[k] = pair_q(bj_[k], r_init);
    }
    int pp = pair_p(tid & 63, r_init), qq = pair_q(tid & 63, r_init);
    for (int r0 = 0; r0 < 127; ++r0) {
      if (tid < 64) {
        float app = sA2[pp * RSA + pp].x, aqq = sA2[qq * RSA + qq].x;
        float2 g = ldc2(sA2, pp, qq);
        float ag2 = g.x * g.x + g.y * g.y;
        float cc = 1.0f, br = 0.0f, bi = 0.0f;
        if (ag2 > 1e-24f) {
          float ag = sqrtf(ag2);
          float ta = (aqq - app) / (2.0f * ag);
          float tt = -copysignf(1.0f, ta) / (fabsf(ta) + sqrtf(1.0f + ta * ta));
          cc = 1.0f / sqrtf(1.0f + tt * tt);
          float tcag = tt * cc / ag;
          br = g.x * tcag; bi = g.y * tcag;
        }
        sprm[tid] = make_float4(cc, br, bi, 0.0f);
        Pg[r0 * 64 + tid] = make_float2(br, bi);   // fire-and-forget (no vmcnt)
      }
      bar_lgkm();   // params visible; all pre-round A reads done (WAR)
#pragma unroll
      for (int k = 0; k < 3; ++k) {
        if (k >= nb) break;
        float2 B00 = ldc2(sA2, pi_[k], pj_[k]);   // tracker addresses: issue now
        float2 B01 = ldc2(sA2, pi_[k], qj_[k]);
        float2 B10 = ldc2(sA2, qi_[k], pj_[k]);
        float2 B11 = ldc2(sA2, qi_[k], qj_[k]);
        float4 Pi = sprm[bi_[k]], Pj = sprm[bj_[k]];
        float ci = Pi.x, bri = Pi.y, bii = Pi.z;
        float cj = Pj.x, brj = Pj.y, bij = Pj.z;
        // left: T = L_i * B
        float t00r = ci * B00.x + (bri * B10.x - bii * B10.y);
        float t00i = ci * B00.y + (bri * B10.y + bii * B10.x);
        float t01r = ci * B01.x + (bri * B11.x - bii * B11.y);
        float t01i = ci * B01.y + (bri * B11.y + bii * B11.x);
        float t10r = ci * B10.x - (bri * B00.x + bii * B00.y);
        float t10i = ci * B10.y - (bri * B00.y - bii * B00.x);
        float t11r = ci * B11.x - (bri * B01.x + bii * B01.y);
        float t11i = ci * B11.y - (bri * B01.y - bii * B01.x);
        // right: C = T * R_j
        stc2(sA2, pi_[k], pj_[k],
             cj * t00r + (brj * t01r + bij * t01i),
             cj * t00i + (brj * t01i - bij * t01r));
        stc2(sA2, pi_[k], qj_[k],
             cj * t01r - (brj * t00r - bij * t00i),
             cj * t01i - (brj * t00i + bij * t00r));
        stc2(sA2, qi_[k], pj_[k],
             cj * t10r + (brj * t11r + bij * t11i),
             cj * t10i + (brj * t11i - bij * t11r));
        stc2(sA2, qi_[k], qj_[k],
             cj * t11r - (brj * t10r - bij * t10i),
             cj * t11i - (brj * t10i + bij * t10r));
      }
      bar_lgkm();   // RAW: writes visible before next round's reads
      // step trackers to next round (uniform branch)
      if (fwd) {
#pragma unroll
        for (int k = 0; k < 3; ++k) {
          pi_[k] = (pi_[k] == 0) ? 0 : ((pi_[k] == 127) ? 1 : pi_[k] + 1);
          qi_[k] = (qi_[k] == 127) ? 1 : qi_[k] + 1;
          pj_[k] = (pj_[k] == 0) ? 0 : ((pj_[k] == 127) ? 1 : pj_[k] + 1);
          qj_[k] = (qj_[k] == 127) ? 1 : qj_[k] + 1;
        }
        pp = (pp == 0) ? 0 : ((pp == 127) ? 1 : pp + 1);
        qq = (qq == 127) ? 1 : qq + 1;
      } else {
#pragma unroll
        for (int k = 0; k < 3; ++k) {
          pi_[k] = (pi_[k] == 0) ? 0 : ((pi_[k] == 1) ? 127 : pi_[k] - 1);
          qi_[k] = (qi_[k] == 1) ? 127 : qi_[k] - 1;
          pj_[k] = (pj_[k] == 0) ? 0 : ((pj_[k] == 1) ? 127 : pj_[k] - 1);
          qj_[k] = (qj_[k] == 1) ? 127 : qj_[k] - 1;
        }
        pp = (pp == 0) ? 0 : ((pp == 1) ? 127 : pp - 1);
        qq = (qq == 1) ? 127 : qq - 1;
      }
    }
    // publish sweep s params: RELEASE drains wave0's outstanding Pg stores
    // (all issued by wave 0) and performs agent-scope writeback.
    if (tid == 0) {
      __hip_atomic_store(&flags[b * SWEEPS + s], (unsigned)(it + 1),
                         __ATOMIC_RELEASE, __HIP_MEMORY_SCOPE_AGENT);
    }
  }

  // fused rankd (diag is canonical); A is NOT written back (dead after this)
  if (tid < NDIM) {
    float wj = sA2[tid * RSA + tid].x;
    int rank = 0;
    for (int k2 = 0; k2 < NDIM; ++k2) {
      float wk = sA2[k2 * RSA + k2].x;
      rank += (wk < wj) || (wk == wj && k2 < tid);
    }
    double mv = minv[(it * BATCH + b) * NDIM + rank];
    double v = (double)wj + mv;
    if (v < 0.0) v = 0.0;
    d1[b * NDIM + tid] = v;
    d2[b * NDIM + tid] = v - (double)wj;
  }
}

// Theta = V diag(d1) V^H ; Lamda = (1-e/r) Lamda + e * V diag(d2) V^H.
__global__ __launch_bounds__(256) void update_kernel(
    const float2* U, const double* d1, const double* d2,
    const float* rho, const float* eta, int it,
    double2* Theta, double2* Lamda) {
  __shared__ float ViRe[32][33], ViIm[32][33];
  __shared__ float VkRe[32][33], VkIm[32][33];
  __shared__ double s1[32], s2[32];
  int blk = blockIdx.x;
  int b = blk >> 4, tile = blk & 15, ti = tile >> 2, tk = tile & 3;
  int tid = threadIdx.x;
  int lk = tid & 31, lig = tid >> 5;
  double r = (double)rho[it], e = (double)eta[it];
  double a1x[4] = {0, 0, 0, 0}, a1y[4] = {0, 0, 0, 0};
  double a2x[4] = {0, 0, 0, 0}, a2y[4] = {0, 0, 0, 0};
  const float2* Ub = U + (size_t)b * NSQ;
  for (int jc = 0; jc < 4; ++jc) {
    for (int e2 = tid; e2 < 1024; e2 += 256) {
      int rr = e2 & 31, cc2 = e2 >> 5;
      float2 v1 = Ub[(jc * 32 + cc2) * NDIM + ti * 32 + rr];
      ViRe[rr][cc2] = v1.x; ViIm[rr][cc2] = v1.y;
      float2 v2 = Ub[(jc * 32 + cc2) * NDIM + tk * 32 + rr];
      VkRe[rr][cc2] = v2.x; VkIm[rr][cc2] = v2.y;
    }
    if (tid < 32) {
      s1[tid] = d1[b * NDIM + jc * 32 + tid];
      s2[tid] = d2[b * NDIM + jc * 32 + tid];
    }
    __syncthreads();
#pragma unroll
    for (int uo = 0; uo < 4; ++uo) {
      int li = lig + uo * 8;
      double ax = a1x[uo], ay = a1y[uo], bx = a2x[uo], by = a2y[uo];
      for (int jj = 0; jj < 32; ++jj) {
        float var = ViRe[li][jj], vai = ViIm[li][jj];
        float vbr = VkRe[lk][jj], vbi = VkIm[lk][jj];
        double pr = (double)(var * vbr + vai * vbi);
        double pi = (double)(vai * vbr - var * vbi);
        ax += s1[jj] * pr; ay += s1[jj] * pi;
        bx += s2[jj] * pr; by += s2[jj] * pi;
      }
      a1x[uo] = ax; a1y[uo] = ay; a2x[uo] = bx; a2y[uo] = by;
    }
    __syncthreads();
  }
  double lf = 1.0 - e / r;
#pragma unroll
  for (int uo = 0; uo < 4; ++uo) {
    int gi = ti * 32 + lig + uo * 8, gk = tk * 32 + lk;
    size_t idx = (size_t)b * NSQ + gi * NDIM + gk;
    Theta[idx] = make_double2(a1x[uo], a1y[uo]);
    double2 Lold = Lamda[idx];
    Lamda[idx] = make_double2(lf * Lold.x + e * a2x[uo], lf * Lold.y + e * a2y[uo]);
  }
}

// OUTPUT (float32 real parts): T[i][j] = u[|i-j|].re ; uvec.re = u.re
__global__ void writeout_kernel(const double2* u, float* out) {
  int tid = blockIdx.x * 256 + threadIdx.x;
  if (tid >= OUT_ELEMS) return;
  double re;
  if (tid < BATCH * MDIM * MDIM) {
    int b = tid >> 12, rem = tid & 4095, i = rem >> 6, j = rem & 63;
    int d = j - i;
    re = u[b * MDIM + (d >= 0 ? d : -d)].x;
  } else {
    int k2 = tid - BATCH * MDIM * MDIM;
    int b = k2 >> 6, kk = k2 & 63;
    re = u[b * MDIM + kk].x;
  }
  out[tid] = (float)re;
}

// ------------------------------- launch ------------------------------------
extern "C" void kernel_launch(void* const* d_in, const int* in_sizes, int n_in,
                              void* d_out, int out_size, void* d_ws, size_t ws_size,
                              hipStream_t stream) {
  const float* Yre = (const float*)d_in[0];
  const float* Yim = (const float*)d_in[1];
  const float* rho = (const float*)d_in[2];
  const float* tau = (const float*)d_in[3];
  const float* eta = (const float*)d_in[4];
  float* out = (float*)d_out;

  char* ws = (char*)d_ws;
  size_t off = 0;
  auto take = [&](size_t bytes) -> char* {
    char* p = ws + off;
    off += (bytes + 255) & ~(size_t)255;
    return p;
  };
  double2* u     = (double2*)take((size_t)BATCH * MDIM * sizeof(double2));
  double*  minv  = (double*)take((size_t)KITER * BATCH * NDIM * sizeof(double));
  double*  d1    = (double*)take((size_t)BATCH * NDIM * sizeof(double));
  double*  d2    = (double*)take((size_t)BATCH * NDIM * sizeof(double));
  double2* Lamda = (double2*)take((size_t)BATCH * NSQ * sizeof(double2));  // 16.8 MB
  double2* Theta = (double2*)take((size_t)BATCH * NSQ * sizeof(double2));  // 16.8 MB
  float2*  A32   = (float2*)take((size_t)BATCH * NSQ * sizeof(float2));    //  8.4 MB
  float2*  U32   = (float2*)take((size_t)BATCH * NSQ * sizeof(float2));    //  8.4 MB
  float2*  prm   = (float2*)take((size_t)SWEEPS * BATCH * 127 * 64 * sizeof(float2)); // 29.4 MB
  unsigned* flags = (unsigned*)take((size_t)BATCH * SWEEPS * sizeof(unsigned));
  (void)in_sizes; (void)n_in; (void)ws_size; (void)out_size;  // ~80.5 MB total

  hipFuncSetAttribute((const void*)combined_all_kernel,
                      hipFuncAttributeMaxDynamicSharedMemorySize, JAC_LDS_BYTES);

  zero_kernel<<<2048, 256, 0, stream>>>((double*)Theta, (size_t)BATCH * NSQ * 2);
  zero_kernel<<<2048, 256, 0, stream>>>((double*)Lamda, (size_t)BATCH * NSQ * 2);
  flags_zero_kernel<<<1, 512, 0, stream>>>(flags);
  prng_kernel<<<(KITER * BATCH * NDIM + 255) / 256, 256, 0, stream>>>(minv);

  for (int it = 0; it < KITER - 1; ++it) {
    compute_u_kernel<<<16, 256, 0, stream>>>(Theta, Lamda, rho, tau, it, u);
    assemble_kernel<<<BATCH * NSQ / 256, 256, 0, stream>>>(Theta, Lamda, u, Yre, Yim,
                                                           rho, tau, it, A32);
    combined_all_kernel<<<BATCH + 2 * BATCH, 1024, JAC_LDS_BYTES, stream>>>(
        A32, U32, prm, flags, minv, it, d1, d2);
    update_kernel<<<BATCH * 16, 256, 0, stream>>>(U32, d1, d2, rho, eta, it, Theta, Lamda);
  }
  compute_u_kernel<<<16, 256, 0, stream>>>(Theta, Lamda, rho, tau, KITER - 1, u);
  writeout_kernel<<<(OUT_ELEMS + 255) / 256, 256, 0, stream>>>(u, out);
}

// Round 5
// 15896.382 us; speedup vs baseline: 1.5039x; 1.1780x over previous
//
#include <hip/hip_runtime.h>
#include <stdint.h>

// ---------------------------------------------------------------------------
// AnmNetwork: ADMM-like complex PSD iteration. B=64, m=l=64, n=128, K=10.
//  * Sita = V relu(w + minv[rank]) V^H  (second eigh mathematically redundant)
//  * Lamda_new = (1 - eta/rho) Lamda + eta * V diag(relu(w+m)-w) V^H
//  * Output depends only on state entering iteration K-1 -> 9 eigh rounds.
//  * PRNG: JAX threefry2x32 partitionable counters (bit-exact, R5).
// R17 = R16 (sweep fusion, 1024 thr, AoS b64, trackers, lgkm barriers) +
// PARAM PIPELINING (R16 post-mortem: round is LDS-queue + serial-param
// bound; wave0's ~500cyc param phase stalls 15 waves every round):
//  * Round split [B1: 189 band blocks (bj-bi<=2), 1/thread | bar |
//    B2: 1891 rest blocks || wave0 computes params for round r+1 | bar].
//  * Slot identities p_ln(r+1)=p_{ln+1}(r), q_ln(r+1)=q_{ln-1}(r) (and
//    mirrored for backward sweeps; edges ln=0,63 verified) place ALL param
//    inputs in band blocks -> P reads fresh post-B1 values, bit-exact.
//  * sprm double-buffered [2][64]; Pg written one round ahead; per-sweep
//    prologue computes seq(0) params. Same 2 barriers/round.
// State (Theta/Lamda), PRNG, u, writeout stay fp64. SWEEPS=7.
// ---------------------------------------------------------------------------

#define BATCH 64
#define MDIM 64
#define LDIM 64
#define NDIM 128
#define NSQ (NDIM * NDIM)
#define KITER 10
#define SWEEPS 7
#define RSA 129                                 // A row stride (float2 units)
#define JAC_LDS_BYTES (NDIM * RSA * (int)sizeof(float2))   // 132,096 B
#define RCH 12                                  // replay chunk col stride (dwords, 48B)
#define OUT_ELEMS 266240   // 64*64*64 (T) + 64*64 (uvec), f32 real parts

// ----------------------------- threefry2x32 --------------------------------
__device__ __forceinline__ void tf_block(unsigned k0, unsigned k1,
                                         unsigned& x0, unsigned& x1) {
  unsigned k2 = k0 ^ k1 ^ 0x1BD11BDAu;
  x0 += k0; x1 += k1;
#define TF_R(r) { x0 += x1; x1 = (x1 << (r)) | (x1 >> (32 - (r))); x1 ^= x0; }
  TF_R(13) TF_R(15) TF_R(26) TF_R(6)
  x0 += k1; x1 += k2 + 1u;
  TF_R(17) TF_R(29) TF_R(16) TF_R(24)
  x0 += k2; x1 += k0 + 2u;
  TF_R(13) TF_R(15) TF_R(26) TF_R(6)
  x0 += k0; x1 += k1 + 3u;
  TF_R(17) TF_R(29) TF_R(16) TF_R(24)
  x0 += k1; x1 += k2 + 4u;
  TF_R(13) TF_R(15) TF_R(26) TF_R(6)
  x0 += k2; x1 += k0 + 5u;
#undef TF_R
}

// ------------------------------- erfinv (f64) ------------------------------
__device__ double erfinv_d(double x) {
  double w = -log1p(-x * x);
  double p;
  if (w < 6.25) {
    w -= 3.125;
    const double c[23] = {
      -3.6444120640178196996e-21, -1.685059138182016589e-19,
      1.2858480715256400167e-18,  1.115787767802518096e-17,
      -1.333171662854620906e-16,  2.0972767875968561637e-17,
      6.6376381343583238325e-15,  -4.0545662729752068639e-14,
      -8.1519341976054721522e-14, 2.6335093153082322977e-12,
      -1.2975133253453532498e-11, -5.4154120542946279317e-11,
      1.051212273321532285e-09,   -4.1126339803469836976e-09,
      -2.9070369957882005086e-08, 4.2347877827932403518e-07,
      -1.3654692000834678645e-06, -1.3882523362786468719e-05,
      1.8673420803405714802e-04,  -7.4070253416626697512e-04,
      -6.0336708714301490533e-03, 2.4015818242558961693e-01,
      1.6536545626831027356e+00};
    p = c[0];
#pragma unroll
    for (int i = 1; i < 23; ++i) p = p * w + c[i];
  } else if (w < 16.0) {
    double s = sqrt(w) - 3.25;
    const double c[19] = {
      2.2137376921775787049e-09,  9.0756561938885390979e-08,
      -2.7517406297064545428e-07, 1.8239629214389227755e-08,
      1.5027403968909827627e-06,  -4.013867526981545969e-06,
      2.9234449089955446044e-06,  1.2475304481671778723e-05,
      -4.7318229009055733981e-05, 6.8284851459573175448e-05,
      2.4031110387097893999e-05,  -3.5503752036284748449e-04,
      9.5328937973738049703e-04,  -1.6882755560235047313e-03,
      2.4914420961078508066e-03,  -3.7512085075692412107e-03,
      5.3709145535900636051e-03,  1.0052589676941592334e+00,
      3.0838856104922207635e+00};
    p = c[0];
#pragma unroll
    for (int i = 1; i < 19; ++i) p = p * s + c[i];
  } else {
    double s = sqrt(w) - 5.0;
    const double c[17] = {
      -2.7109920616438573243e-11, -2.5556418169965252055e-10,
      1.5076572693500548083e-09,  -3.7894654401267369937e-09,
      7.6157012080783393804e-09,  -1.4960026627149240478e-08,
      2.9147953450901080826e-08,  -6.7711997758452339498e-08,
      2.2900482228026654717e-07,  -9.9298272942317002539e-07,
      4.5260625972231537039e-06,  -1.9681778105531670567e-05,
      7.5995277030017761139e-05,  -2.1503011930044477347e-04,
      -1.3871931833623122026e-04, 1.0103004648645343977e+00,
      4.8499064014085844221e+00};
    p = c[0];
#pragma unroll
    for (int i = 1; i < 17; ++i) p = p * s + c[i];
  }
  double z = p * x;
  const double spi2 = 0.8862269254527580;  // sqrt(pi)/2
  double ax = fabs(x);
#pragma unroll
  for (int nr = 0; nr < 2; ++nr) {
    if (ax > 0.9375) {
      double az = fabs(z);
      double corr = (erfc(az) - (1.0 - ax)) * spi2 * exp(az * az);
      az += corr;
      z = copysign(az, x);
    } else {
      z -= (erf(z) - x) * spi2 * exp(z * z);
    }
  }
  return z;
}

// ------------------------------- kernels -----------------------------------
__global__ void zero_kernel(double* p, size_t n) {
  size_t i = (size_t)blockIdx.x * blockDim.x + threadIdx.x;
  size_t stride = (size_t)gridDim.x * blockDim.x;
  for (; i < n; i += stride) p[i] = 0.0;
}

__global__ void flags_zero_kernel(unsigned* flags) {
  int tid = threadIdx.x;
  if (tid < BATCH * SWEEPS) flags[tid] = 0u;
}

__global__ void prng_kernel(double* minv) {
  int tid = blockIdx.x * blockDim.x + threadIdx.x;
  if (tid >= KITER * BATCH * NDIM) return;
  int it = tid / (BATCH * NDIM);
  int i = tid % (BATCH * NDIM);
  unsigned nk0 = 0u, nk1 = (unsigned)it;
  tf_block(0u, 42u, nk0, nk1);                       // fold_in
  unsigned c0 = 0u, c1 = (unsigned)i;                // partitionable counter
  tf_block(nk0, nk1, c0, c1);
  unsigned long long bits = ((unsigned long long)c0 << 32) | (unsigned long long)c1;
  unsigned long long fb = (bits >> 12) | 0x3FF0000000000000ull;
  double f = __builtin_bit_cast(double, fb) - 1.0;
  const double lo = __builtin_bit_cast(double, 0xBFEFFFFFFFFFFFFFull);
  double uu = f * 2.0 + lo;
  if (uu < lo) uu = lo;
  minv[tid] = 1.4142135623730951 * erfinv_d(uu);
}

__global__ void compute_u_kernel(const double2* Theta, const double2* Lamda,
                                 const float* rho, const float* tau, int it,
                                 double2* u) {
  int tid = blockIdx.x * blockDim.x + threadIdx.x;
  if (tid >= BATCH * MDIM) return;
  int b = tid / MDIM, kk = tid % MDIM;
  double r = (double)rho[it], t = (double)tau[it];
  const double2* Lb = Lamda + (size_t)b * NSQ;
  const double2* Tb = Theta + (size_t)b * NSQ;
  double ar = 0.0, ai = 0.0;
  for (int i = 0; i + kk < MDIM; ++i) {
    double2 L = Lb[i * NDIM + i + kk];
    double2 Th = Tb[i * NDIM + i + kk];
    ar += L.x + r * Th.x;
    ai += L.y + r * Th.y;
  }
  if (kk == 0) ar += -(t * 0.5) * (double)MDIM;
  double s = 1.0 / ((double)(MDIM - kk) * r);
  u[b * MDIM + kk] = make_double2(ar * s, ai * s);
}

// A32 = fp32(StackM - Lamda/r)   (U init lives in combined_all: U = I)
__global__ void assemble_kernel(const double2* Theta, const double2* Lamda,
                                const double2* u, const float* Yre, const float* Yim,
                                const float* rho, const float* tau, int it,
                                float2* A32) {
  int tid = blockIdx.x * 256 + threadIdx.x;
  if (tid >= BATCH * NSQ) return;
  int b = tid / NSQ, rem = tid % NSQ, i = rem / NDIM, j = rem % NDIM;
  double r = (double)rho[it], t = (double)tau[it];
  size_t idx = (size_t)b * NSQ + rem;
  double2 L = Lamda[idx], Th = Theta[idx];
  double axr, axi;
  if (i < MDIM && j < MDIM) {
    int d = j - i;
    double2 uv = u[b * MDIM + (d >= 0 ? d : -d)];
    double uy = (d >= 0) ? uv.y : -uv.y;
    axr = uv.x - L.x / r;
    axi = uy - L.y / r;
  } else if (i < MDIM) {
    double yr = (double)Yre[(b * MDIM + i) * LDIM + (j - MDIM)];
    double yi = (double)Yim[(b * MDIM + i) * LDIM + (j - MDIM)];
    double inv = 1.0 / (1.0 + 2.0 * r);
    axr = (yr + 2.0 * L.x + 2.0 * r * Th.x) * inv - L.x / r;
    axi = (yi + 2.0 * L.y + 2.0 * r * Th.y) * inv - L.y / r;
  } else if (j < MDIM) {
    double yr = (double)Yre[(b * MDIM + j) * LDIM + (i - MDIM)];
    double yi = -(double)Yim[(b * MDIM + j) * LDIM + (i - MDIM)];
    double inv = 1.0 / (1.0 + 2.0 * r);
    axr = (yr + 2.0 * L.x + 2.0 * r * Th.x) * inv - L.x / r;
    axi = (yi + 2.0 * L.y + 2.0 * r * Th.y) * inv - L.y / r;
  } else {
    axr = Th.x - ((i == j) ? t / (2.0 * r) : 0.0);
    axi = Th.y;
  }
  A32[idx] = make_float2((float)axr, (float)axi);
}

__device__ __forceinline__ int pair_p(int j, int r) {
  return (j == 0) ? 0 : 1 + (j - 1 + r) % 127;
}
__device__ __forceinline__ int pair_q(int j, int r) {
  return 1 + (126 - j + r) % 127;
}

// Canonical-upper accessors (AoS float2 plane, stride RSA) -> single b64 op.
__device__ __forceinline__ float2 ldc2(const float2* sA, int r, int c) {
  int rr = r <= c ? r : c, cc = r <= c ? c : r;
  float2 v = sA[rr * RSA + cc];
  if (r > c) v.y = -v.y;
  return v;
}
__device__ __forceinline__ void stc2(float2* sA, int r, int c, float zr, float zi) {
  int rr = r <= c ? r : c, cc = r <= c ? c : r;
  sA[rr * RSA + cc] = make_float2(zr, (r <= c) ? zi : -zi);
}

// Raw barrier: drain own LDS ops only -- wave0's Pg global stores stay in
// flight (drained once per sweep by the RELEASE atomic on the same wave).
__device__ __forceinline__ void bar_lgkm() {
  asm volatile("s_waitcnt lgkmcnt(0)" ::: "memory");
  __builtin_amdgcn_s_barrier();
}

// Fused dispatch: blocks 0..63 jacobi (all 7 sweeps, A LDS-resident, params
// released per sweep via device-scope flags); blocks 64..191 replay (U chunk
// LDS-resident across all 7 sweeps, init to I, acquire-spin per sweep).
__global__ __launch_bounds__(1024) void combined_all_kernel(
    const float2* __restrict__ A, float2* __restrict__ U,
    float2* __restrict__ prm,        // [SWEEPS][BATCH][127][64]
    unsigned* __restrict__ flags,    // [BATCH][SWEEPS]
    const double* __restrict__ minv, int it,
    double* __restrict__ d1, double* __restrict__ d2) {
  extern __shared__ float smem[];
  int tid = threadIdx.x;

  if (blockIdx.x >= BATCH) {
    // ------------------------- replay path --------------------------------
    if (tid >= 512) return;   // 8 working waves; no block barriers here
    int rb = blockIdx.x - BATCH;
    int wv = tid >> 6, ln = tid & 63;
    int b = rb >> 1, half = rb & 1;
    int col0 = (half * 8 + wv) * 8;
    float* cre = smem + wv * (2 * NDIM * RCH);
    float* cim = cre + NDIM * RCH;
    // U = I (chunk init in LDS; no global load)
    for (int e = ln; e < NDIM * 8; e += 64) {
      int row = e >> 3, c = e & 7;
      cre[row * RCH + c] = (row == col0 + c) ? 1.0f : 0.0f;
      cim[row * RCH + c] = 0.0f;
    }
    for (int s = 0; s < SWEEPS; ++s) {
      const float2* Pg = prm + ((size_t)s * BATCH + b) * (127 * 64);
      if (ln == 0) {   // per-wave acquire spin (waves are independent)
        while (__hip_atomic_load(&flags[b * SWEEPS + s], __ATOMIC_ACQUIRE,
                                 __HIP_MEMORY_SCOPE_AGENT) != (unsigned)(it + 1)) {
          __builtin_amdgcn_s_sleep(8);
        }
      }
      // wave64 lockstep reconvergence: all lanes proceed after ln0's acquire
      float2 prmv = Pg[ln];   // round 0 params, prefetched
      for (int r0 = 0; r0 < 127; ++r0) {
        int r = (s & 1) ? (126 - r0) : r0;
        int p = pair_p(ln, r), q = pair_q(ln, r);
        float2 nxt = prmv;
        if (r0 < 126) nxt = Pg[(r0 + 1) * 64 + ln];   // prefetch next round
        float br = prmv.x, bi = prmv.y;
        float cc = sqrtf(fmaxf(0.0f, 1.0f - br * br - bi * bi));
        float4* Rp = (float4*)(cre + p * RCH);   // 48B rows: 16B-aligned
        float4* Rq = (float4*)(cre + q * RCH);
        float4* Ip = (float4*)(cim + p * RCH);
        float4* Iq = (float4*)(cim + q * RCH);
        float4 pr0 = Rp[0], pr1 = Rp[1], pim0 = Ip[0], pim1 = Ip[1];
        float4 qr0 = Rq[0], qr1 = Rq[1], qim0 = Iq[0], qim1 = Iq[1];
#define ROTC(UPX, UPY, UQX, UQY) { float upx = UPX, upy = UPY, uqx = UQX, uqy = UQY; \
    UPX = cc * upx + (br * uqx + bi * uqy);  /* U_p <- c U_p + conj(sb) U_q */       \
    UPY = cc * upy + (br * uqy - bi * uqx);                                          \
    UQX = cc * uqx - (br * upx - bi * upy);  /* U_q <- c U_q - sb U_p */             \
    UQY = cc * uqy - (br * upy + bi * upx); }
        ROTC(pr0.x, pim0.x, qr0.x, qim0.x)
        ROTC(pr0.y, pim0.y, qr0.y, qim0.y)
        ROTC(pr0.z, pim0.z, qr0.z, qim0.z)
        ROTC(pr0.w, pim0.w, qr0.w, qim0.w)
        ROTC(pr1.x, pim1.x, qr1.x, qim1.x)
        ROTC(pr1.y, pim1.y, qr1.y, qim1.y)
        ROTC(pr1.z, pim1.z, qr1.z, qim1.z)
        ROTC(pr1.w, pim1.w, qr1.w, qim1.w)
#undef ROTC
        Rp[0] = pr0; Rp[1] = pr1; Ip[0] = pim0; Ip[1] = pim1;
        Rq[0] = qr0; Rq[1] = qr1; Iq[0] = qim0; Iq[1] = qim1;
        prmv = nxt;
        __builtin_amdgcn_wave_barrier();
      }
    }
    float2* Ug = U + (size_t)b * NSQ;
    for (int e = ln; e < NDIM * 8; e += 64) {
      int row = e >> 3, c = e & 7;
      Ug[row * NDIM + col0 + c] = make_float2(cre[row * RCH + c], cim[row * RCH + c]);
    }
    return;
  }

  // --------------------------- jacobi path --------------------------------
  // 1024 threads. Per round: [B1: 189 band blocks (bj-bi<=2), one per thread
  // 64..252 | bar | B2: 1891 rest blocks (threads 64..1023, 1-2 each) ||
  // wave0 computes params for round r+1 from fresh band cells | bar].
  float2* sA2 = (float2*)smem;    // 128 x 129 float2 (AoS re,im)
  __shared__ float4 sprm2[2][64]; // double-buffered {c, br, bi, 0}
  int b = blockIdx.x;
  const float2* Ag = A + (size_t)b * NSQ;
  for (int i = tid; i < NSQ; i += 1024) {
    sA2[(i >> 7) * RSA + (i & 127)] = Ag[i];
  }
  // ---- static ownership ----
  // band block (bj-bi<=2): threads 64..252, one each
  bool hasband = (tid >= 64 && tid < 64 + 189);
  int bb_i = 0, bb_j = 0;
  if (hasband) {
    int e = tid - 64;
    if (e < 64)       { bb_i = e;      bb_j = e; }
    else if (e < 127) { bb_i = e - 64; bb_j = bb_i + 1; }
    else              { bb_i = e - 127; bb_j = bb_i + 2; }
  }
  // rest blocks (bj-bi>=3): 1891 over threads 64..1023, indices t-64, t-64+960
  int nrest = 0;
  int rb_i[2], rb_j[2];
  rb_i[0] = rb_i[1] = 0; rb_j[0] = rb_j[1] = 0;
  if (tid >= 64) {
#pragma unroll
    for (int m = 0; m < 2; ++m) {
      int e = (tid - 64) + 960 * m;
      if (e < 1891) {
        // base(bi) = 61*bi - bi*(bi-1)/2 ; bj = bi + 3 + (e - base)
        int i = 0;
        while (i < 60 && (61 * (i + 1) - ((i + 1) * i) / 2) <= e) ++i;
        rb_i[nrest] = i;
        rb_j[nrest] = i + 3 + (e - (61 * i - (i * (i - 1)) / 2));
        ++nrest;
      }
    }
  }
  __syncthreads();

  for (int s = 0; s < SWEEPS; ++s) {
    float2* Pg = prm + ((size_t)s * BATCH + b) * (127 * 64);
    const bool fwd = !(s & 1);
    const int r_init = fwd ? 0 : 126;
    // tracker step helpers (fwd: rows +1 with wraps; bwd: rows -1)
    auto stepP = [&](int x) {
      return fwd ? ((x == 0) ? 0 : ((x == 127) ? 1 : x + 1))
                 : ((x == 0) ? 0 : ((x == 1) ? 127 : x - 1));
    };
    auto stepQ = [&](int x) {
      return fwd ? ((x == 127) ? 1 : x + 1)
                 : ((x == 1) ? 127 : x - 1);
    };
    // row trackers at r_init
    int bpi = pair_p(bb_i, r_init), bqi = pair_q(bb_i, r_init);
    int bpj = pair_p(bb_j, r_init), bqj = pair_q(bb_j, r_init);
    int rpi[2], rqi[2], rpj[2], rqj[2];
#pragma unroll
    for (int m = 0; m < 2; ++m) {
      rpi[m] = pair_p(rb_i[m], r_init); rqi[m] = pair_q(rb_i[m], r_init);
      rpj[m] = pair_p(rb_j[m], r_init); rqj[m] = pair_q(rb_j[m], r_init);
    }
    // param compute helper (wave0 lanes): rows (pp,qq) -> sprm2[buf] + Pg[pos]
    auto pcalc = [&](int pp, int qq, int buf, int pos) {
      float app = sA2[pp * RSA + pp].x, aqq = sA2[qq * RSA + qq].x;
      float2 g = ldc2(sA2, pp, qq);
      float ag2 = g.x * g.x + g.y * g.y;
      float cc = 1.0f, br = 0.0f, bi = 0.0f;
      if (ag2 > 1e-24f) {
        float ag = sqrtf(ag2);
        float ta = (aqq - app) / (2.0f * ag);
        float tt = -copysignf(1.0f, ta) / (fabsf(ta) + sqrtf(1.0f + ta * ta));
        cc = 1.0f / sqrtf(1.0f + tt * tt);
        float tcag = tt * cc / ag;
        br = g.x * tcag; bi = g.y * tcag;
      }
      sprm2[buf][tid] = make_float4(cc, br, bi, 0.0f);
      Pg[pos * 64 + tid] = make_float2(br, bi);   // fire-and-forget
    };
    // 2x2 block rotate (reads/writes canonical cells; params from sprm2[buf])
    auto rot = [&](int bi_s, int bj_s, int pi_, int qi_, int pj_, int qj_, int buf) {
      float2 B00 = ldc2(sA2, pi_, pj_);
      float2 B01 = ldc2(sA2, pi_, qj_);
      float2 B10 = ldc2(sA2, qi_, pj_);
      float2 B11 = ldc2(sA2, qi_, qj_);
      float4 Pi = sprm2[buf][bi_s], Pj = sprm2[buf][bj_s];
      float ci = Pi.x, bri = Pi.y, bii = Pi.z;
      float cj = Pj.x, brj = Pj.y, bij = Pj.z;
      // left: T = L_i * B
      float t00r = ci * B00.x + (bri * B10.x - bii * B10.y);
      float t00i = ci * B00.y + (bri * B10.y + bii * B10.x);
      float t01r = ci * B01.x + (bri * B11.x - bii * B11.y);
      float t01i = ci * B01.y + (bri * B11.y + bii * B11.x);
      float t10r = ci * B10.x - (bri * B00.x + bii * B00.y);
      float t10i = ci * B10.y - (bri * B00.y - bii * B00.x);
      float t11r = ci * B11.x - (bri * B01.x + bii * B01.y);
      float t11i = ci * B11.y - (bri * B01.y - bii * B01.x);
      // right: C = T * R_j
      stc2(sA2, pi_, pj_,
           cj * t00r + (brj * t01r + bij * t01i),
           cj * t00i + (brj * t01i - bij * t01r));
      stc2(sA2, pi_, qj_,
           cj * t01r - (brj * t00r - bij * t00i),
           cj * t01i - (brj * t00i + bij * t00r));
      stc2(sA2, qi_, pj_,
           cj * t10r + (brj * t11r + bij * t11i),
           cj * t10i + (brj * t11i - bij * t11r));
      stc2(sA2, qi_, qj_,
           cj * t11r - (brj * t10r - bij * t10i),
           cj * t11i - (brj * t10i + bij * t10r));
    };
    // ---- sweep prologue: params for seq(0) into sprm2[0]; init next-rows --
    int ppn = 0, qqn = 0;
    if (tid < 64) {
      int pp0 = pair_p(tid, r_init), qq0 = pair_q(tid, r_init);
      pcalc(pp0, qq0, 0, 0);
      ppn = stepP(pp0); qqn = stepQ(qq0);   // rows at seq(1)
    }
    bar_lgkm();
    int cur = 0;
    // ---- round loop ----
    for (int r0 = 0; r0 < 127; ++r0) {
      // phase B1: band blocks (params r0 from sprm2[cur])
      if (hasband) rot(bb_i, bb_j, bpi, bqi, bpj, bqj, cur);
      bar_lgkm();   // band cells final; pre-round reads of band cells done
      // phase B2 || P(r0+1)
      if (tid < 64) {
        if (r0 < 126) {
          pcalc(ppn, qqn, cur ^ 1, r0 + 1);
          ppn = stepP(ppn); qqn = stepQ(qqn);
        }
      } else {
        if (nrest > 0) rot(rb_i[0], rb_j[0], rpi[0], rqi[0], rpj[0], rqj[0], cur);
        if (nrest > 1) rot(rb_i[1], rb_j[1], rpi[1], rqi[1], rpj[1], rqj[1], cur);
      }
      bar_lgkm();   // rest writes + sprm2[cur^1] visible
      cur ^= 1;
      // step trackers to next round
      bpi = stepP(bpi); bqi = stepQ(bqi); bpj = stepP(bpj); bqj = stepQ(bqj);
#pragma unroll
      for (int m = 0; m < 2; ++m) {
        rpi[m] = stepP(rpi[m]); rqi[m] = stepQ(rqi[m]);
        rpj[m] = stepP(rpj[m]); rqj[m] = stepQ(rqj[m]);
      }
    }
    // publish sweep s params: RELEASE drains wave0's outstanding Pg stores
    // (all issued by wave 0) and performs agent-scope writeback.
    if (tid == 0) {
      __hip_atomic_store(&flags[b * SWEEPS + s], (unsigned)(it + 1),
                         __ATOMIC_RELEASE, __HIP_MEMORY_SCOPE_AGENT);
    }
  }

  // fused rankd (diag is canonical); A is NOT written back (dead after this)
  if (tid < NDIM) {
    float wj = sA2[tid * RSA + tid].x;
    int rank = 0;
    for (int k2 = 0; k2 < NDIM; ++k2) {
      float wk = sA2[k2 * RSA + k2].x;
      rank += (wk < wj) || (wk == wj && k2 < tid);
    }
    double mv = minv[(it * BATCH + b) * NDIM + rank];
    double v = (double)wj + mv;
    if (v < 0.0) v = 0.0;
    d1[b * NDIM + tid] = v;
    d2[b * NDIM + tid] = v - (double)wj;
  }
}

// Theta = V diag(d1) V^H ; Lamda = (1-e/r) Lamda + e * V diag(d2) V^H.
__global__ __launch_bounds__(256) void update_kernel(
    const float2* U, const double* d1, const double* d2,
    const float* rho, const float* eta, int it,
    double2* Theta, double2* Lamda) {
  __shared__ float ViRe[32][33], ViIm[32][33];
  __shared__ float VkRe[32][33], VkIm[32][33];
  __shared__ double s1[32], s2[32];
  int blk = blockIdx.x;
  int b = blk >> 4, tile = blk & 15, ti = tile >> 2, tk = tile & 3;
  int tid = threadIdx.x;
  int lk = tid & 31, lig = tid >> 5;
  double r = (double)rho[it], e = (double)eta[it];
  double a1x[4] = {0, 0, 0, 0}, a1y[4] = {0, 0, 0, 0};
  double a2x[4] = {0, 0, 0, 0}, a2y[4] = {0, 0, 0, 0};
  const float2* Ub = U + (size_t)b * NSQ;
  for (int jc = 0; jc < 4; ++jc) {
    for (int e2 = tid; e2 < 1024; e2 += 256) {
      int rr = e2 & 31, cc2 = e2 >> 5;
      float2 v1 = Ub[(jc * 32 + cc2) * NDIM + ti * 32 + rr];
      ViRe[rr][cc2] = v1.x; ViIm[rr][cc2] = v1.y;
      float2 v2 = Ub[(jc * 32 + cc2) * NDIM + tk * 32 + rr];
      VkRe[rr][cc2] = v2.x; VkIm[rr][cc2] = v2.y;
    }
    if (tid < 32) {
      s1[tid] = d1[b * NDIM + jc * 32 + tid];
      s2[tid] = d2[b * NDIM + jc * 32 + tid];
    }
    __syncthreads();
#pragma unroll
    for (int uo = 0; uo < 4; ++uo) {
      int li = lig + uo * 8;
      double ax = a1x[uo], ay = a1y[uo], bx = a2x[uo], by = a2y[uo];
      for (int jj = 0; jj < 32; ++jj) {
        float var = ViRe[li][jj], vai = ViIm[li][jj];
        float vbr = VkRe[lk][jj], vbi = VkIm[lk][jj];
        double pr = (double)(var * vbr + vai * vbi);
        double pi = (double)(vai * vbr - var * vbi);
        ax += s1[jj] * pr; ay += s1[jj] * pi;
        bx += s2[jj] * pr; by += s2[jj] * pi;
      }
      a1x[uo] = ax; a1y[uo] = ay; a2x[uo] = bx; a2y[uo] = by;
    }
    __syncthreads();
  }
  double lf = 1.0 - e / r;
#pragma unroll
  for (int uo = 0; uo < 4; ++uo) {
    int gi = ti * 32 + lig + uo * 8, gk = tk * 32 + lk;
    size_t idx = (size_t)b * NSQ + gi * NDIM + gk;
    Theta[idx] = make_double2(a1x[uo], a1y[uo]);
    double2 Lold = Lamda[idx];
    Lamda[idx] = make_double2(lf * Lold.x + e * a2x[uo], lf * Lold.y + e * a2y[uo]);
  }
}

// OUTPUT (float32 real parts): T[i][j] = u[|i-j|].re ; uvec.re = u.re
__global__ void writeout_kernel(const double2* u, float* out) {
  int tid = blockIdx.x * 256 + threadIdx.x;
  if (tid >= OUT_ELEMS) return;
  double re;
  if (tid < BATCH * MDIM * MDIM) {
    int b = tid >> 12, rem = tid & 4095, i = rem >> 6, j = rem & 63;
    int d = j - i;
    re = u[b * MDIM + (d >= 0 ? d : -d)].x;
  } else {
    int k2 = tid - BATCH * MDIM * MDIM;
    int b = k2 >> 6, kk = k2 & 63;
    re = u[b * MDIM + kk].x;
  }
  out[tid] = (float)re;
}

// ------------------------------- launch ------------------------------------
extern "C" void kernel_launch(void* const* d_in, const int* in_sizes, int n_in,
                              void* d_out, int out_size, void* d_ws, size_t ws_size,
                              hipStream_t stream) {
  const float* Yre = (const float*)d_in[0];
  const float* Yim = (const float*)d_in[1];
  const float* rho = (const float*)d_in[2];
  const float* tau = (const float*)d_in[3];
  const float* eta = (const float*)d_in[4];
  float* out = (float*)d_out;

  char* ws = (char*)d_ws;
  size_t off = 0;
  auto take = [&](size_t bytes) -> char* {
    char* p = ws + off;
    off += (bytes + 255) & ~(size_t)255;
    return p;
  };
  double2* u     = (double2*)take((size_t)BATCH * MDIM * sizeof(double2));
  double*  minv  = (double*)take((size_t)KITER * BATCH * NDIM * sizeof(double));
  double*  d1    = (double*)take((size_t)BATCH * NDIM * sizeof(double));
  double*  d2    = (double*)take((size_t)BATCH * NDIM * sizeof(double));
  double2* Lamda = (double2*)take((size_t)BATCH * NSQ * sizeof(double2));  // 16.8 MB
  double2* Theta = (double2*)take((size_t)BATCH * NSQ * sizeof(double2));  // 16.8 MB
  float2*  A32   = (float2*)take((size_t)BATCH * NSQ * sizeof(float2));    //  8.4 MB
  float2*  U32   = (float2*)take((size_t)BATCH * NSQ * sizeof(float2));    //  8.4 MB
  float2*  prm   = (float2*)take((size_t)SWEEPS * BATCH * 127 * 64 * sizeof(float2)); // 29.4 MB
  unsigned* flags = (unsigned*)take((size_t)BATCH * SWEEPS * sizeof(unsigned));
  (void)in_sizes; (void)n_in; (void)ws_size; (void)out_size;  // ~80.5 MB total

  hipFuncSetAttribute((const void*)combined_all_kernel,
                      hipFuncAttributeMaxDynamicSharedMemorySize, JAC_LDS_BYTES);

  zero_kernel<<<2048, 256, 0, stream>>>((double*)Theta, (size_t)BATCH * NSQ * 2);
  zero_kernel<<<2048, 256, 0, stream>>>((double*)Lamda, (size_t)BATCH * NSQ * 2);
  flags_zero_kernel<<<1, 512, 0, stream>>>(flags);
  prng_kernel<<<(KITER * BATCH * NDIM + 255) / 256, 256, 0, stream>>>(minv);

  for (int it = 0; it < KITER - 1; ++it) {
    compute_u_kernel<<<16, 256, 0, stream>>>(Theta, Lamda, rho, tau, it, u);
    assemble_kernel<<<BATCH * NSQ / 256, 256, 0, stream>>>(Theta, Lamda, u, Yre, Yim,
                                                           rho, tau, it, A32);
    combined_all_kernel<<<BATCH + 2 * BATCH, 1024, JAC_LDS_BYTES, stream>>>(
        A32, U32, prm, flags, minv, it, d1, d2);
    update_kernel<<<BATCH * 16, 256, 0, stream>>>(U32, d1, d2, rho, eta, it, Theta, Lamda);
  }
  compute_u_kernel<<<16, 256, 0, stream>>>(Theta, Lamda, rho, tau, KITER - 1, u);
  writeout_kernel<<<(OUT_ELEMS + 255) / 256, 256, 0, stream>>>(u, out);
}

// Round 6
// 14637.569 us; speedup vs baseline: 1.6332x; 1.0860x over previous
//
#include <hip/hip_runtime.h>
#include <stdint.h>

// ---------------------------------------------------------------------------
// AnmNetwork: ADMM-like complex PSD iteration. B=64, m=l=64, n=128, K=10.
//  * Sita = V relu(w + minv[rank]) V^H  (second eigh mathematically redundant)
//  * Lamda_new = (1 - eta/rho) Lamda + eta * V diag(relu(w+m)-w) V^H
//  * Output depends only on state entering iteration K-1 -> 9 eigh rounds.
//  * PRNG: JAX threefry2x32 partitionable counters (bit-exact, R5).
// R18 = R17 (sweep fusion, band/rest split, param pipelining) + 1-BARRIER
// ROUND + BANK FIX (R17 post-mortem: 2 barriers/round ~500cyc, diag cells
// on even bank-pairs 8-way conflict):
//  * Wave0 owns ALL 189 band blocks (lane ln: (ln,ln),(ln,ln+1)[ln<=62],
//    (ln,ln+2)[ln<=61]) and computes P(r+1) right after -- same-wave LDS is
//    in-order (replay has relied on cross-lane in-wave ordering since R12),
//    so the B1 barrier disappears: [wave0 B1+P || waves1-15 rest] | bar.
//    Band/rest cell sets are disjoint (cell <-> unique slot-pair) -> rest
//    waves never touch band cells; bit-identical arithmetic.
//  * RSA 129 -> 130 float2: bank-pair (2r+c)&15; diagonal (3p)&15 covers all
//    16 pairs (was (r+c)&15 -> diag on 8 even pairs = 8-way conflict).
//  * Rest threads: two blocks merged read-8 -> compute -> write-8 (disjoint
//    cells; removes one serial read-latency per round).
// State (Theta/Lamda), PRNG, u, writeout stay fp64. SWEEPS=7.
// ---------------------------------------------------------------------------

#define BATCH 64
#define MDIM 64
#define LDIM 64
#define NDIM 128
#define NSQ (NDIM * NDIM)
#define KITER 10
#define SWEEPS 7
#define RSA 130                                 // A row stride (float2 units)
#define JAC_LDS_BYTES (NDIM * RSA * (int)sizeof(float2))   // 133,120 B
#define RCH 12                                  // replay chunk col stride (dwords, 48B)
#define OUT_ELEMS 266240   // 64*64*64 (T) + 64*64 (uvec), f32 real parts

// ----------------------------- threefry2x32 --------------------------------
__device__ __forceinline__ void tf_block(unsigned k0, unsigned k1,
                                         unsigned& x0, unsigned& x1) {
  unsigned k2 = k0 ^ k1 ^ 0x1BD11BDAu;
  x0 += k0; x1 += k1;
#define TF_R(r) { x0 += x1; x1 = (x1 << (r)) | (x1 >> (32 - (r))); x1 ^= x0; }
  TF_R(13) TF_R(15) TF_R(26) TF_R(6)
  x0 += k1; x1 += k2 + 1u;
  TF_R(17) TF_R(29) TF_R(16) TF_R(24)
  x0 += k2; x1 += k0 + 2u;
  TF_R(13) TF_R(15) TF_R(26) TF_R(6)
  x0 += k0; x1 += k1 + 3u;
  TF_R(17) TF_R(29) TF_R(16) TF_R(24)
  x0 += k1; x1 += k2 + 4u;
  TF_R(13) TF_R(15) TF_R(26) TF_R(6)
  x0 += k2; x1 += k0 + 5u;
#undef TF_R
}

// ------------------------------- erfinv (f64) ------------------------------
__device__ double erfinv_d(double x) {
  double w = -log1p(-x * x);
  double p;
  if (w < 6.25) {
    w -= 3.125;
    const double c[23] = {
      -3.6444120640178196996e-21, -1.685059138182016589e-19,
      1.2858480715256400167e-18,  1.115787767802518096e-17,
      -1.333171662854620906e-16,  2.0972767875968561637e-17,
      6.6376381343583238325e-15,  -4.0545662729752068639e-14,
      -8.1519341976054721522e-14, 2.6335093153082322977e-12,
      -1.2975133253453532498e-11, -5.4154120542946279317e-11,
      1.051212273321532285e-09,   -4.1126339803469836976e-09,
      -2.9070369957882005086e-08, 4.2347877827932403518e-07,
      -1.3654692000834678645e-06, -1.3882523362786468719e-05,
      1.8673420803405714802e-04,  -7.4070253416626697512e-04,
      -6.0336708714301490533e-03, 2.4015818242558961693e-01,
      1.6536545626831027356e+00};
    p = c[0];
#pragma unroll
    for (int i = 1; i < 23; ++i) p = p * w + c[i];
  } else if (w < 16.0) {
    double s = sqrt(w) - 3.25;
    const double c[19] = {
      2.2137376921775787049e-09,  9.0756561938885390979e-08,
      -2.7517406297064545428e-07, 1.8239629214389227755e-08,
      1.5027403968909827627e-06,  -4.013867526981545969e-06,
      2.9234449089955446044e-06,  1.2475304481671778723e-05,
      -4.7318229009055733981e-05, 6.8284851459573175448e-05,
      2.4031110387097893999e-05,  -3.5503752036284748449e-04,
      9.5328937973738049703e-04,  -1.6882755560235047313e-03,
      2.4914420961078508066e-03,  -3.7512085075692412107e-03,
      5.3709145535900636051e-03,  1.0052589676941592334e+00,
      3.0838856104922207635e+00};
    p = c[0];
#pragma unroll
    for (int i = 1; i < 19; ++i) p = p * s + c[i];
  } else {
    double s = sqrt(w) - 5.0;
    const double c[17] = {
      -2.7109920616438573243e-11, -2.5556418169965252055e-10,
      1.5076572693500548083e-09,  -3.7894654401267369937e-09,
      7.6157012080783393804e-09,  -1.4960026627149240478e-08,
      2.9147953450901080826e-08,  -6.7711997758452339498e-08,
      2.2900482228026654717e-07,  -9.9298272942317002539e-07,
      4.5260625972231537039e-06,  -1.9681778105531670567e-05,
      7.5995277030017761139e-05,  -2.1503011930044477347e-04,
      -1.3871931833623122026e-04, 1.0103004648645343977e+00,
      4.8499064014085844221e+00};
    p = c[0];
#pragma unroll
    for (int i = 1; i < 17; ++i) p = p * s + c[i];
  }
  double z = p * x;
  const double spi2 = 0.8862269254527580;  // sqrt(pi)/2
  double ax = fabs(x);
#pragma unroll
  for (int nr = 0; nr < 2; ++nr) {
    if (ax > 0.9375) {
      double az = fabs(z);
      double corr = (erfc(az) - (1.0 - ax)) * spi2 * exp(az * az);
      az += corr;
      z = copysign(az, x);
    } else {
      z -= (erf(z) - x) * spi2 * exp(z * z);
    }
  }
  return z;
}

// ------------------------------- kernels -----------------------------------
__global__ void zero_kernel(double* p, size_t n) {
  size_t i = (size_t)blockIdx.x * blockDim.x + threadIdx.x;
  size_t stride = (size_t)gridDim.x * blockDim.x;
  for (; i < n; i += stride) p[i] = 0.0;
}

__global__ void flags_zero_kernel(unsigned* flags) {
  int tid = threadIdx.x;
  if (tid < BATCH * SWEEPS) flags[tid] = 0u;
}

__global__ void prng_kernel(double* minv) {
  int tid = blockIdx.x * blockDim.x + threadIdx.x;
  if (tid >= KITER * BATCH * NDIM) return;
  int it = tid / (BATCH * NDIM);
  int i = tid % (BATCH * NDIM);
  unsigned nk0 = 0u, nk1 = (unsigned)it;
  tf_block(0u, 42u, nk0, nk1);                       // fold_in
  unsigned c0 = 0u, c1 = (unsigned)i;                // partitionable counter
  tf_block(nk0, nk1, c0, c1);
  unsigned long long bits = ((unsigned long long)c0 << 32) | (unsigned long long)c1;
  unsigned long long fb = (bits >> 12) | 0x3FF0000000000000ull;
  double f = __builtin_bit_cast(double, fb) - 1.0;
  const double lo = __builtin_bit_cast(double, 0xBFEFFFFFFFFFFFFFull);
  double uu = f * 2.0 + lo;
  if (uu < lo) uu = lo;
  minv[tid] = 1.4142135623730951 * erfinv_d(uu);
}

__global__ void compute_u_kernel(const double2* Theta, const double2* Lamda,
                                 const float* rho, const float* tau, int it,
                                 double2* u) {
  int tid = blockIdx.x * blockDim.x + threadIdx.x;
  if (tid >= BATCH * MDIM) return;
  int b = tid / MDIM, kk = tid % MDIM;
  double r = (double)rho[it], t = (double)tau[it];
  const double2* Lb = Lamda + (size_t)b * NSQ;
  const double2* Tb = Theta + (size_t)b * NSQ;
  double ar = 0.0, ai = 0.0;
  for (int i = 0; i + kk < MDIM; ++i) {
    double2 L = Lb[i * NDIM + i + kk];
    double2 Th = Tb[i * NDIM + i + kk];
    ar += L.x + r * Th.x;
    ai += L.y + r * Th.y;
  }
  if (kk == 0) ar += -(t * 0.5) * (double)MDIM;
  double s = 1.0 / ((double)(MDIM - kk) * r);
  u[b * MDIM + kk] = make_double2(ar * s, ai * s);
}

// A32 = fp32(StackM - Lamda/r)   (U init lives in combined_all: U = I)
__global__ void assemble_kernel(const double2* Theta, const double2* Lamda,
                                const double2* u, const float* Yre, const float* Yim,
                                const float* rho, const float* tau, int it,
                                float2* A32) {
  int tid = blockIdx.x * 256 + threadIdx.x;
  if (tid >= BATCH * NSQ) return;
  int b = tid / NSQ, rem = tid % NSQ, i = rem / NDIM, j = rem % NDIM;
  double r = (double)rho[it], t = (double)tau[it];
  size_t idx = (size_t)b * NSQ + rem;
  double2 L = Lamda[idx], Th = Theta[idx];
  double axr, axi;
  if (i < MDIM && j < MDIM) {
    int d = j - i;
    double2 uv = u[b * MDIM + (d >= 0 ? d : -d)];
    double uy = (d >= 0) ? uv.y : -uv.y;
    axr = uv.x - L.x / r;
    axi = uy - L.y / r;
  } else if (i < MDIM) {
    double yr = (double)Yre[(b * MDIM + i) * LDIM + (j - MDIM)];
    double yi = (double)Yim[(b * MDIM + i) * LDIM + (j - MDIM)];
    double inv = 1.0 / (1.0 + 2.0 * r);
    axr = (yr + 2.0 * L.x + 2.0 * r * Th.x) * inv - L.x / r;
    axi = (yi + 2.0 * L.y + 2.0 * r * Th.y) * inv - L.y / r;
  } else if (j < MDIM) {
    double yr = (double)Yre[(b * MDIM + j) * LDIM + (i - MDIM)];
    double yi = -(double)Yim[(b * MDIM + j) * LDIM + (i - MDIM)];
    double inv = 1.0 / (1.0 + 2.0 * r);
    axr = (yr + 2.0 * L.x + 2.0 * r * Th.x) * inv - L.x / r;
    axi = (yi + 2.0 * L.y + 2.0 * r * Th.y) * inv - L.y / r;
  } else {
    axr = Th.x - ((i == j) ? t / (2.0 * r) : 0.0);
    axi = Th.y;
  }
  A32[idx] = make_float2((float)axr, (float)axi);
}

__device__ __forceinline__ int pair_p(int j, int r) {
  return (j == 0) ? 0 : 1 + (j - 1 + r) % 127;
}
__device__ __forceinline__ int pair_q(int j, int r) {
  return 1 + (126 - j + r) % 127;
}

// Canonical-upper accessors (AoS float2 plane, stride RSA) -> single b64 op.
__device__ __forceinline__ float2 ldc2(const float2* sA, int r, int c) {
  int rr = r <= c ? r : c, cc = r <= c ? c : r;
  float2 v = sA[rr * RSA + cc];
  if (r > c) v.y = -v.y;
  return v;
}
__device__ __forceinline__ void stc2(float2* sA, int r, int c, float zr, float zi) {
  int rr = r <= c ? r : c, cc = r <= c ? c : r;
  sA[rr * RSA + cc] = make_float2(zr, (r <= c) ? zi : -zi);
}

// Raw barrier: drain own LDS ops only -- wave0's Pg global stores stay in
// flight (drained once per sweep by the RELEASE atomic on the same wave).
__device__ __forceinline__ void bar_lgkm() {
  asm volatile("s_waitcnt lgkmcnt(0)" ::: "memory");
  __builtin_amdgcn_s_barrier();
}

// Fused dispatch: blocks 0..63 jacobi (all 7 sweeps, A LDS-resident, params
// released per sweep via device-scope flags); blocks 64..191 replay (U chunk
// LDS-resident across all 7 sweeps, init to I, acquire-spin per sweep).
__global__ __launch_bounds__(1024) void combined_all_kernel(
    const float2* __restrict__ A, float2* __restrict__ U,
    float2* __restrict__ prm,        // [SWEEPS][BATCH][127][64]
    unsigned* __restrict__ flags,    // [BATCH][SWEEPS]
    const double* __restrict__ minv, int it,
    double* __restrict__ d1, double* __restrict__ d2) {
  extern __shared__ float smem[];
  int tid = threadIdx.x;

  if (blockIdx.x >= BATCH) {
    // ------------------------- replay path --------------------------------
    if (tid >= 512) return;   // 8 working waves; no block barriers here
    int rb = blockIdx.x - BATCH;
    int wv = tid >> 6, ln = tid & 63;
    int b = rb >> 1, half = rb & 1;
    int col0 = (half * 8 + wv) * 8;
    float* cre = smem + wv * (2 * NDIM * RCH);
    float* cim = cre + NDIM * RCH;
    // U = I (chunk init in LDS; no global load)
    for (int e = ln; e < NDIM * 8; e += 64) {
      int row = e >> 3, c = e & 7;
      cre[row * RCH + c] = (row == col0 + c) ? 1.0f : 0.0f;
      cim[row * RCH + c] = 0.0f;
    }
    for (int s = 0; s < SWEEPS; ++s) {
      const float2* Pg = prm + ((size_t)s * BATCH + b) * (127 * 64);
      if (ln == 0) {   // per-wave acquire spin (waves are independent)
        while (__hip_atomic_load(&flags[b * SWEEPS + s], __ATOMIC_ACQUIRE,
                                 __HIP_MEMORY_SCOPE_AGENT) != (unsigned)(it + 1)) {
          __builtin_amdgcn_s_sleep(8);
        }
      }
      // wave64 lockstep reconvergence: all lanes proceed after ln0's acquire
      float2 prmv = Pg[ln];   // round 0 params, prefetched
      for (int r0 = 0; r0 < 127; ++r0) {
        int r = (s & 1) ? (126 - r0) : r0;
        int p = pair_p(ln, r), q = pair_q(ln, r);
        float2 nxt = prmv;
        if (r0 < 126) nxt = Pg[(r0 + 1) * 64 + ln];   // prefetch next round
        float br = prmv.x, bi = prmv.y;
        float cc = sqrtf(fmaxf(0.0f, 1.0f - br * br - bi * bi));
        float4* Rp = (float4*)(cre + p * RCH);   // 48B rows: 16B-aligned
        float4* Rq = (float4*)(cre + q * RCH);
        float4* Ip = (float4*)(cim + p * RCH);
        float4* Iq = (float4*)(cim + q * RCH);
        float4 pr0 = Rp[0], pr1 = Rp[1], pim0 = Ip[0], pim1 = Ip[1];
        float4 qr0 = Rq[0], qr1 = Rq[1], qim0 = Iq[0], qim1 = Iq[1];
#define ROTC(UPX, UPY, UQX, UQY) { float upx = UPX, upy = UPY, uqx = UQX, uqy = UQY; \
    UPX = cc * upx + (br * uqx + bi * uqy);  /* U_p <- c U_p + conj(sb) U_q */       \
    UPY = cc * upy + (br * uqy - bi * uqx);                                          \
    UQX = cc * uqx - (br * upx - bi * upy);  /* U_q <- c U_q - sb U_p */             \
    UQY = cc * uqy - (br * upy + bi * upx); }
        ROTC(pr0.x, pim0.x, qr0.x, qim0.x)
        ROTC(pr0.y, pim0.y, qr0.y, qim0.y)
        ROTC(pr0.z, pim0.z, qr0.z, qim0.z)
        ROTC(pr0.w, pim0.w, qr0.w, qim0.w)
        ROTC(pr1.x, pim1.x, qr1.x, qim1.x)
        ROTC(pr1.y, pim1.y, qr1.y, qim1.y)
        ROTC(pr1.z, pim1.z, qr1.z, qim1.z)
        ROTC(pr1.w, pim1.w, qr1.w, qim1.w)
#undef ROTC
        Rp[0] = pr0; Rp[1] = pr1; Ip[0] = pim0; Ip[1] = pim1;
        Rq[0] = qr0; Rq[1] = qr1; Iq[0] = qim0; Iq[1] = qim1;
        prmv = nxt;
        __builtin_amdgcn_wave_barrier();
      }
    }
    float2* Ug = U + (size_t)b * NSQ;
    for (int e = ln; e < NDIM * 8; e += 64) {
      int row = e >> 3, c = e & 7;
      Ug[row * NDIM + col0 + c] = make_float2(cre[row * RCH + c], cim[row * RCH + c]);
    }
    return;
  }

  // --------------------------- jacobi path --------------------------------
  // 1024 threads. Per round (ONE barrier): wave0 rotates all 189 band blocks
  // (lane ln: (ln,ln),(ln,ln+1)[ln<=62],(ln,ln+2)[ln<=61]) then computes
  // P(r+1) from its own fresh band cells (same-wave LDS in-order); waves
  // 1..15 rotate the 1891 rest blocks (2 each, read-8/compute/write-8).
  float2* sA2 = (float2*)smem;    // 128 x 130 float2 (AoS re,im)
  __shared__ float4 sprm2[2][64]; // double-buffered {c, br, bi, 0}
  int b = blockIdx.x;
  const float2* Ag = A + (size_t)b * NSQ;
  for (int i = tid; i < NSQ; i += 1024) {
    sA2[(i >> 7) * RSA + (i & 127)] = Ag[i];
  }
  // rest blocks (bj-bi>=3): 1891 over threads 64..1023, indices t-64, t-64+960
  int nrest = 0;
  int rb_i[2], rb_j[2];
  rb_i[0] = rb_i[1] = 0; rb_j[0] = rb_j[1] = 0;
  if (tid >= 64) {
#pragma unroll
    for (int m = 0; m < 2; ++m) {
      int e = (tid - 64) + 960 * m;
      if (e < 1891) {
        // base(bi) = 61*bi - bi*(bi-1)/2 ; bj = bi + 3 + (e - base)
        int i = 0;
        while (i < 60 && (61 * (i + 1) - ((i + 1) * i) / 2) <= e) ++i;
        rb_i[nrest] = i;
        rb_j[nrest] = i + 3 + (e - (61 * i - (i * (i - 1)) / 2));
        ++nrest;
      }
    }
  }
  int ln = tid;   // wave0 lane = band slot base (valid when tid<64)
  __syncthreads();

  for (int s = 0; s < SWEEPS; ++s) {
    float2* Pg = prm + ((size_t)s * BATCH + b) * (127 * 64);
    const bool fwd = !(s & 1);
    const int r_init = fwd ? 0 : 126;
    auto stepP = [&](int x) {
      return fwd ? ((x == 0) ? 0 : ((x == 127) ? 1 : x + 1))
                 : ((x == 0) ? 0 : ((x == 1) ? 127 : x - 1));
    };
    auto stepQ = [&](int x) {
      return fwd ? ((x == 127) ? 1 : x + 1)
                 : ((x == 1) ? 127 : x - 1);
    };
    // band trackers (wave0): rows p,q for slots ln, ln+1, ln+2
    int bp0 = pair_p(ln, r_init), bq0 = pair_q(ln, r_init);
    int bp1 = pair_p(ln + 1, r_init), bq1 = pair_q(ln + 1, r_init);
    int bp2 = pair_p(ln + 2, r_init), bq2 = pair_q(ln + 2, r_init);
    // rest trackers
    int rpi[2], rqi[2], rpj[2], rqj[2];
#pragma unroll
    for (int m = 0; m < 2; ++m) {
      rpi[m] = pair_p(rb_i[m], r_init); rqi[m] = pair_q(rb_i[m], r_init);
      rpj[m] = pair_p(rb_j[m], r_init); rqj[m] = pair_q(rb_j[m], r_init);
    }
    // param compute helper (wave0 lanes): rows (pp,qq) -> sprm2[buf] + Pg[pos]
    auto pcalc = [&](int pp, int qq, int buf, int pos) {
      float app = sA2[pp * RSA + pp].x, aqq = sA2[qq * RSA + qq].x;
      float2 g = ldc2(sA2, pp, qq);
      float ag2 = g.x * g.x + g.y * g.y;
      float cc = 1.0f, br = 0.0f, bi = 0.0f;
      if (ag2 > 1e-24f) {
        float ag = sqrtf(ag2);
        float ta = (aqq - app) / (2.0f * ag);
        float tt = -copysignf(1.0f, ta) / (fabsf(ta) + sqrtf(1.0f + ta * ta));
        cc = 1.0f / sqrtf(1.0f + tt * tt);
        float tcag = tt * cc / ag;
        br = g.x * tcag; bi = g.y * tcag;
      }
      sprm2[buf][tid] = make_float4(cc, br, bi, 0.0f);
      Pg[pos * 64 + tid] = make_float2(br, bi);   // fire-and-forget
    };
    // single-block rotate (band path)
    auto rot = [&](int bi_s, int bj_s, int pi_, int qi_, int pj_, int qj_, int buf) {
      float2 B00 = ldc2(sA2, pi_, pj_);
      float2 B01 = ldc2(sA2, pi_, qj_);
      float2 B10 = ldc2(sA2, qi_, pj_);
      float2 B11 = ldc2(sA2, qi_, qj_);
      float4 Pi = sprm2[buf][bi_s], Pj = sprm2[buf][bj_s];
      float ci = Pi.x, bri = Pi.y, bii = Pi.z;
      float cj = Pj.x, brj = Pj.y, bij = Pj.z;
      float t00r = ci * B00.x + (bri * B10.x - bii * B10.y);
      float t00i = ci * B00.y + (bri * B10.y + bii * B10.x);
      float t01r = ci * B01.x + (bri * B11.x - bii * B11.y);
      float t01i = ci * B01.y + (bri * B11.y + bii * B11.x);
      float t10r = ci * B10.x - (bri * B00.x + bii * B00.y);
      float t10i = ci * B10.y - (bri * B00.y - bii * B00.x);
      float t11r = ci * B11.x - (bri * B01.x + bii * B01.y);
      float t11i = ci * B11.y - (bri * B01.y - bii * B01.x);
      stc2(sA2, pi_, pj_,
           cj * t00r + (brj * t01r + bij * t01i),
           cj * t00i + (brj * t01i - bij * t01r));
      stc2(sA2, pi_, qj_,
           cj * t01r - (brj * t00r - bij * t00i),
           cj * t01i - (brj * t00i + bij * t00r));
      stc2(sA2, qi_, pj_,
           cj * t10r + (brj * t11r + bij * t11i),
           cj * t10i + (brj * t11i - bij * t11r));
      stc2(sA2, qi_, qj_,
           cj * t11r - (brj * t10r - bij * t10i),
           cj * t11i - (brj * t10i + bij * t10r));
    };
    // compute half of a merged rot (inputs pre-read)
    auto rotc = [&](int bi_s, int bj_s, int pi_, int qi_, int pj_, int qj_, int buf,
                    float2 B00, float2 B01, float2 B10, float2 B11) {
      float4 Pi = sprm2[buf][bi_s], Pj = sprm2[buf][bj_s];
      float ci = Pi.x, bri = Pi.y, bii = Pi.z;
      float cj = Pj.x, brj = Pj.y, bij = Pj.z;
      float t00r = ci * B00.x + (bri * B10.x - bii * B10.y);
      float t00i = ci * B00.y + (bri * B10.y + bii * B10.x);
      float t01r = ci * B01.x + (bri * B11.x - bii * B11.y);
      float t01i = ci * B01.y + (bri * B11.y + bii * B11.x);
      float t10r = ci * B10.x - (bri * B00.x + bii * B00.y);
      float t10i = ci * B10.y - (bri * B00.y - bii * B00.x);
      float t11r = ci * B11.x - (bri * B01.x + bii * B01.y);
      float t11i = ci * B11.y - (bri * B01.y - bii * B01.x);
      stc2(sA2, pi_, pj_,
           cj * t00r + (brj * t01r + bij * t01i),
           cj * t00i + (brj * t01i - bij * t01r));
      stc2(sA2, pi_, qj_,
           cj * t01r - (brj * t00r - bij * t00i),
           cj * t01i - (brj * t00i + bij * t00r));
      stc2(sA2, qi_, pj_,
           cj * t10r + (brj * t11r + bij * t11i),
           cj * t10i + (brj * t11i - bij * t11r));
      stc2(sA2, qi_, qj_,
           cj * t11r - (brj * t10r - bij * t10i),
           cj * t11i - (brj * t10i + bij * t10r));
    };
    // ---- sweep prologue: params for seq(0) into sprm2[0]; init next-rows --
    int ppn = 0, qqn = 0;
    if (tid < 64) {
      int pp0 = pair_p(tid, r_init), qq0 = pair_q(tid, r_init);
      pcalc(pp0, qq0, 0, 0);
      ppn = stepP(pp0); qqn = stepQ(qq0);   // rows at seq(1)
    }
    bar_lgkm();
    int cur = 0;
    // ---- round loop (ONE barrier per round) ----
    for (int r0 = 0; r0 < 127; ++r0) {
      if (tid < 64) {
        // band blocks with params(r0); own-wave writes, in program order
        rot(ln, ln, bp0, bq0, bp0, bq0, cur);
        if (ln <= 62) rot(ln, ln + 1, bp0, bq0, bp1, bq1, cur);
        if (ln <= 61) rot(ln, ln + 2, bp0, bq0, bp2, bq2, cur);
        __builtin_amdgcn_wave_barrier();   // keep compiler order: B1 then P
        if (r0 < 126) {
          pcalc(ppn, qqn, cur ^ 1, r0 + 1);  // reads wave0's fresh band cells
          ppn = stepP(ppn); qqn = stepQ(qqn);
        }
      } else {
        // rest blocks: read all 8 cells, compute, write 8 (disjoint cells)
        float2 B00a, B01a, B10a, B11a, B00b, B01b, B10b, B11b;
        if (nrest > 0) {
          B00a = ldc2(sA2, rpi[0], rpj[0]);
          B01a = ldc2(sA2, rpi[0], rqj[0]);
          B10a = ldc2(sA2, rqi[0], rpj[0]);
          B11a = ldc2(sA2, rqi[0], rqj[0]);
        }
        if (nrest > 1) {
          B00b = ldc2(sA2, rpi[1], rpj[1]);
          B01b = ldc2(sA2, rpi[1], rqj[1]);
          B10b = ldc2(sA2, rqi[1], rpj[1]);
          B11b = ldc2(sA2, rqi[1], rqj[1]);
        }
        if (nrest > 0)
          rotc(rb_i[0], rb_j[0], rpi[0], rqi[0], rpj[0], rqj[0], cur,
               B00a, B01a, B10a, B11a);
        if (nrest > 1)
          rotc(rb_i[1], rb_j[1], rpi[1], rqi[1], rpj[1], rqj[1], cur,
               B00b, B01b, B10b, B11b);
      }
      bar_lgkm();   // all writes + sprm2[cur^1] visible for next round
      cur ^= 1;
      // step trackers to next round
      bp0 = stepP(bp0); bq0 = stepQ(bq0);
      bp1 = stepP(bp1); bq1 = stepQ(bq1);
      bp2 = stepP(bp2); bq2 = stepQ(bq2);
#pragma unroll
      for (int m = 0; m < 2; ++m) {
        rpi[m] = stepP(rpi[m]); rqi[m] = stepQ(rqi[m]);
        rpj[m] = stepP(rpj[m]); rqj[m] = stepQ(rqj[m]);
      }
    }
    // publish sweep s params: RELEASE drains wave0's outstanding Pg stores
    // (all issued by wave 0) and performs agent-scope writeback.
    if (tid == 0) {
      __hip_atomic_store(&flags[b * SWEEPS + s], (unsigned)(it + 1),
                         __ATOMIC_RELEASE, __HIP_MEMORY_SCOPE_AGENT);
    }
  }

  // fused rankd (diag is canonical); A is NOT written back (dead after this)
  if (tid < NDIM) {
    float wj = sA2[tid * RSA + tid].x;
    int rank = 0;
    for (int k2 = 0; k2 < NDIM; ++k2) {
      float wk = sA2[k2 * RSA + k2].x;
      rank += (wk < wj) || (wk == wj && k2 < tid);
    }
    double mv = minv[(it * BATCH + b) * NDIM + rank];
    double v = (double)wj + mv;
    if (v < 0.0) v = 0.0;
    d1[b * NDIM + tid] = v;
    d2[b * NDIM + tid] = v - (double)wj;
  }
}

// Theta = V diag(d1) V^H ; Lamda = (1-e/r) Lamda + e * V diag(d2) V^H.
__global__ __launch_bounds__(256) void update_kernel(
    const float2* U, const double* d1, const double* d2,
    const float* rho, const float* eta, int it,
    double2* Theta, double2* Lamda) {
  __shared__ float ViRe[32][33], ViIm[32][33];
  __shared__ float VkRe[32][33], VkIm[32][33];
  __shared__ double s1[32], s2[32];
  int blk = blockIdx.x;
  int b = blk >> 4, tile = blk & 15, ti = tile >> 2, tk = tile & 3;
  int tid = threadIdx.x;
  int lk = tid & 31, lig = tid >> 5;
  double r = (double)rho[it], e = (double)eta[it];
  double a1x[4] = {0, 0, 0, 0}, a1y[4] = {0, 0, 0, 0};
  double a2x[4] = {0, 0, 0, 0}, a2y[4] = {0, 0, 0, 0};
  const float2* Ub = U + (size_t)b * NSQ;
  for (int jc = 0; jc < 4; ++jc) {
    for (int e2 = tid; e2 < 1024; e2 += 256) {
      int rr = e2 & 31, cc2 = e2 >> 5;
      float2 v1 = Ub[(jc * 32 + cc2) * NDIM + ti * 32 + rr];
      ViRe[rr][cc2] = v1.x; ViIm[rr][cc2] = v1.y;
      float2 v2 = Ub[(jc * 32 + cc2) * NDIM + tk * 32 + rr];
      VkRe[rr][cc2] = v2.x; VkIm[rr][cc2] = v2.y;
    }
    if (tid < 32) {
      s1[tid] = d1[b * NDIM + jc * 32 + tid];
      s2[tid] = d2[b * NDIM + jc * 32 + tid];
    }
    __syncthreads();
#pragma unroll
    for (int uo = 0; uo < 4; ++uo) {
      int li = lig + uo * 8;
      double ax = a1x[uo], ay = a1y[uo], bx = a2x[uo], by = a2y[uo];
      for (int jj = 0; jj < 32; ++jj) {
        float var = ViRe[li][jj], vai = ViIm[li][jj];
        float vbr = VkRe[lk][jj], vbi = VkIm[lk][jj];
        double pr = (double)(var * vbr + vai * vbi);
        double pi = (double)(vai * vbr - var * vbi);
        ax += s1[jj] * pr; ay += s1[jj] * pi;
        bx += s2[jj] * pr; by += s2[jj] * pi;
      }
      a1x[uo] = ax; a1y[uo] = ay; a2x[uo] = bx; a2y[uo] = by;
    }
    __syncthreads();
  }
  double lf = 1.0 - e / r;
#pragma unroll
  for (int uo = 0; uo < 4; ++uo) {
    int gi = ti * 32 + lig + uo * 8, gk = tk * 32 + lk;
    size_t idx = (size_t)b * NSQ + gi * NDIM + gk;
    Theta[idx] = make_double2(a1x[uo], a1y[uo]);
    double2 Lold = Lamda[idx];
    Lamda[idx] = make_double2(lf * Lold.x + e * a2x[uo], lf * Lold.y + e * a2y[uo]);
  }
}

// OUTPUT (float32 real parts): T[i][j] = u[|i-j|].re ; uvec.re = u.re
__global__ void writeout_kernel(const double2* u, float* out) {
  int tid = blockIdx.x * 256 + threadIdx.x;
  if (tid >= OUT_ELEMS) return;
  double re;
  if (tid < BATCH * MDIM * MDIM) {
    int b = tid >> 12, rem = tid & 4095, i = rem >> 6, j = rem & 63;
    int d = j - i;
    re = u[b * MDIM + (d >= 0 ? d : -d)].x;
  } else {
    int k2 = tid - BATCH * MDIM * MDIM;
    int b = k2 >> 6, kk = k2 & 63;
    re = u[b * MDIM + kk].x;
  }
  out[tid] = (float)re;
}

// ------------------------------- launch ------------------------------------
extern "C" void kernel_launch(void* const* d_in, const int* in_sizes, int n_in,
                              void* d_out, int out_size, void* d_ws, size_t ws_size,
                              hipStream_t stream) {
  const float* Yre = (const float*)d_in[0];
  const float* Yim = (const float*)d_in[1];
  const float* rho = (const float*)d_in[2];
  const float* tau = (const float*)d_in[3];
  const float* eta = (const float*)d_in[4];
  float* out = (float*)d_out;

  char* ws = (char*)d_ws;
  size_t off = 0;
  auto take = [&](size_t bytes) -> char* {
    char* p = ws + off;
    off += (bytes + 255) & ~(size_t)255;
    return p;
  };
  double2* u     = (double2*)take((size_t)BATCH * MDIM * sizeof(double2));
  double*  minv  = (double*)take((size_t)KITER * BATCH * NDIM * sizeof(double));
  double*  d1    = (double*)take((size_t)BATCH * NDIM * sizeof(double));
  double*  d2    = (double*)take((size_t)BATCH * NDIM * sizeof(double));
  double2* Lamda = (double2*)take((size_t)BATCH * NSQ * sizeof(double2));  // 16.8 MB
  double2* Theta = (double2*)take((size_t)BATCH * NSQ * sizeof(double2));  // 16.8 MB
  float2*  A32   = (float2*)take((size_t)BATCH * NSQ * sizeof(float2));    //  8.4 MB
  float2*  U32   = (float2*)take((size_t)BATCH * NSQ * sizeof(float2));    //  8.4 MB
  float2*  prm   = (float2*)take((size_t)SWEEPS * BATCH * 127 * 64 * sizeof(float2)); // 29.4 MB
  unsigned* flags = (unsigned*)take((size_t)BATCH * SWEEPS * sizeof(unsigned));
  (void)in_sizes; (void)n_in; (void)ws_size; (void)out_size;  // ~80.5 MB total

  hipFuncSetAttribute((const void*)combined_all_kernel,
                      hipFuncAttributeMaxDynamicSharedMemorySize, JAC_LDS_BYTES);

  zero_kernel<<<2048, 256, 0, stream>>>((double*)Theta, (size_t)BATCH * NSQ * 2);
  zero_kernel<<<2048, 256, 0, stream>>>((double*)Lamda, (size_t)BATCH * NSQ * 2);
  flags_zero_kernel<<<1, 512, 0, stream>>>(flags);
  prng_kernel<<<(KITER * BATCH * NDIM + 255) / 256, 256, 0, stream>>>(minv);

  for (int it = 0; it < KITER - 1; ++it) {
    compute_u_kernel<<<16, 256, 0, stream>>>(Theta, Lamda, rho, tau, it, u);
    assemble_kernel<<<BATCH * NSQ / 256, 256, 0, stream>>>(Theta, Lamda, u, Yre, Yim,
                                                           rho, tau, it, A32);
    combined_all_kernel<<<BATCH + 2 * BATCH, 1024, JAC_LDS_BYTES, stream>>>(
        A32, U32, prm, flags, minv, it, d1, d2);
    update_kernel<<<BATCH * 16, 256, 0, stream>>>(U32, d1, d2, rho, eta, it, Theta, Lamda);
  }
  compute_u_kernel<<<16, 256, 0, stream>>>(Theta, Lamda, rho, tau, KITER - 1, u);
  writeout_kernel<<<(OUT_ELEMS + 255) / 256, 256, 0, stream>>>(u, out);
}